// Round 1
// baseline (890.991 us; speedup 1.0000x reference)
//
#include <hip/hip_runtime.h>
#include <cstdint>
#include <cstddef>

#define V_   32000
#define DS_  64
#define DF_  256
#define H_   8
#define L_   1024
#define B_   2
#define NB_  512
#define BL_  2048
#define EPS_ 1e-5f

__device__ __forceinline__ float sigmoidf_(float x) { return 1.f / (1.f + __expf(-x)); }

// Block-wide sum reduction over 256 threads.
__device__ __forceinline__ float block_reduce_sum(float v, float* red) {
    int t = threadIdx.x;
    red[t] = v;
    __syncthreads();
    for (int s = 128; s > 0; s >>= 1) {
        if (t < s) red[t] += red[t + s];
        __syncthreads();
    }
    float r = red[0];
    __syncthreads();
    return r;
}

// ---------------------------------------------------------------------------
// Gather: mu = tok_mu[tok]+pos_mu, iv = exp(-log_var[tok]), alpha = sigmoid(ra),
// feat = tok_features[tok]
// grid BL_, block 256
__global__ __launch_bounds__(256) void k_gather(
    const int* __restrict__ tok, const float* __restrict__ tok_mu,
    const float* __restrict__ tok_lv, const float* __restrict__ tok_ra,
    const float* __restrict__ tok_f, const float* __restrict__ pos_mu,
    float* __restrict__ mu, float* __restrict__ iv,
    float* __restrict__ alpha, float* __restrict__ feat) {
    int row = blockIdx.x;            // b*L + l
    int l = row & (L_ - 1);
    int t = threadIdx.x;
    int v = tok[row];
    if (t < DS_) {
        mu[(size_t)row * DS_ + t] = tok_mu[(size_t)v * DS_ + t] + pos_mu[l * DS_ + t];
        iv[(size_t)row * DS_ + t] = __expf(-tok_lv[(size_t)v * DS_ + t]);
    }
    feat[(size_t)row * DF_ + t] = tok_f[(size_t)v * DF_ + t];
    if (t == 0) alpha[row] = sigmoidf_(tok_ra[v]);
}

// query[b][d] = mean over l of mu.  grid B_, block 256
__global__ __launch_bounds__(256) void k_query(const float* __restrict__ mu,
                                               float* __restrict__ query) {
    __shared__ float red[256];
    int b = blockIdx.x, t = threadIdx.x;
    int d = t & 63, c = t >> 6;
    float s = 0.f;
    for (int l = c; l < L_; l += 4) s += mu[((size_t)b * L_ + l) * DS_ + d];
    red[t] = s;
    __syncthreads();
    if (c == 0)
        query[b * DS_ + d] = (red[d] + red[64 + d] + red[128 + d] + red[192 + d]) * (1.f / L_);
}

// Blob mixture: grid B_, block 256
__global__ __launch_bounds__(256) void k_blob(
    const float* __restrict__ query, const float* __restrict__ blob_mu,
    const float* __restrict__ blob_lv, const float* __restrict__ blob_ra,
    const float* __restrict__ blob_f, float* __restrict__ blobm,
    float* __restrict__ tres) {
    __shared__ float sw[NB_];
    __shared__ float sq[DS_];
    int b = blockIdx.x, t = threadIdx.x;
    if (t < DS_) sq[t] = query[b * DS_ + t];
    __syncthreads();
    for (int n = t; n < NB_; n += 256) {
        float d2 = 0.f;
        for (int d = 0; d < DS_; ++d) {
            float diff = sq[d] - blob_mu[n * DS_ + d];
            d2 += __expf(-blob_lv[n * DS_ + d]) * diff * diff;
        }
        sw[n] = sigmoidf_(blob_ra[n]) * __expf(-0.5f * d2);
    }
    __syncthreads();
    if (t == 0) {
        float T = 1.f;
        for (int n = 0; n < NB_; ++n) {
            float a = sw[n];
            sw[n] = a * T;
            T *= (1.f - a);
        }
        tres[b] = T;
    }
    __syncthreads();
    float acc = 0.f;
    for (int n = 0; n < NB_; ++n) acc += sw[n] * blob_f[n * DF_ + t];
    blobm[b * DF_ + t] = acc;
}

// Attention with streaming composite weights + early exit.
// One wave per (b,h,i).  grid 4096 blocks x 256 threads (4 waves/block).
__global__ __launch_bounds__(256) void k_attn(
    const float* __restrict__ q, const float* __restrict__ mu,
    const float* __restrict__ iv, const float* __restrict__ alpha,
    const float* __restrict__ feat, float* __restrict__ mcat) {
    int gtid = blockIdx.x * 256 + threadIdx.x;
    int wid = gtid >> 6;
    int lane = threadIdx.x & 63;
    int b = wid / (H_ * L_);
    int rem = wid % (H_ * L_);
    int h = rem / L_;
    int i = rem % L_;

    float qd = q[((size_t)(b * L_ + i)) * (H_ * DS_) + h * DS_ + lane];
    const float* mub = mu + (size_t)b * L_ * DS_;
    const float* ivb = iv + (size_t)b * L_ * DS_;
    const float* ab  = alpha + b * L_;
    const float* fb  = feat + (size_t)b * L_ * DF_;

    float a0 = 0.f, a1 = 0.f, a2 = 0.f, a3 = 0.f;
    float T = 1.f;
    for (int j = 0; j <= i; ++j) {
        float diff = qd - mub[(size_t)j * DS_ + lane];
        float e = ivb[(size_t)j * DS_ + lane] * diff * diff;
        #pragma unroll
        for (int s = 1; s < 64; s <<= 1) e += __shfl_xor(e, s, 64);
        float a = ab[j] * __expf(-0.5f * e);
        float w = a * T;
        T *= (1.f - a);
        const float* fr = fb + (size_t)j * DF_;
        a0 += w * fr[lane];
        a1 += w * fr[lane + 64];
        a2 += w * fr[lane + 128];
        a3 += w * fr[lane + 192];
        if (T < 1e-12f) break;   // wave-uniform: residual mass below fp32 noise
    }
    float* o = mcat + ((size_t)(b * L_ + i)) * (H_ * DF_) + h * DF_;
    o[lane] = a0; o[lane + 64] = a1; o[lane + 128] = a2; o[lane + 192] = a3;
}

// Generic fp32 tiled GEMM: C(M,N) = A(M,K) @ W(N,K)^T + bias(N)
// block = 256 threads, tile TM x TN, per-thread RM x RN
template <int TM, int TN, int TK, int RM, int RN>
__global__ __launch_bounds__(256) void gemm_nt(
    const float* __restrict__ A, const float* __restrict__ W,
    const float* __restrict__ bias, float* __restrict__ C,
    int M, int N, int K) {
    __shared__ float As[TK][TM + 4];
    __shared__ float Ws[TK][TN + 4];
    const int tid = threadIdx.x;
    const int m0 = blockIdx.x * TM;
    const int n0 = blockIdx.y * TN;
    constexpr int TX = TN / RN;
    const int tm = (tid / TX) * RM;
    const int tn = (tid % TX) * RN;
    float acc[RM][RN] = {};

    for (int k0 = 0; k0 < K; k0 += TK) {
        constexpr int AE = TM * TK / 256;
        #pragma unroll
        for (int e = 0; e < AE; e += 4) {
            int idx = tid * AE + e;
            int r = idx / TK, c = idx % TK;
            const float4 v = *reinterpret_cast<const float4*>(&A[(size_t)(m0 + r) * K + k0 + c]);
            As[c][r] = v.x; As[c + 1][r] = v.y; As[c + 2][r] = v.z; As[c + 3][r] = v.w;
        }
        constexpr int WE = TN * TK / 256;
        #pragma unroll
        for (int e = 0; e < WE; e += 4) {
            int idx = tid * WE + e;
            int r = idx / TK, c = idx % TK;
            const float4 v = *reinterpret_cast<const float4*>(&W[(size_t)(n0 + r) * K + k0 + c]);
            Ws[c][r] = v.x; Ws[c + 1][r] = v.y; Ws[c + 2][r] = v.z; Ws[c + 3][r] = v.w;
        }
        __syncthreads();
        #pragma unroll
        for (int k = 0; k < TK; ++k) {
            float ra[RM], rw[RN];
            #pragma unroll
            for (int x = 0; x < RM; ++x) ra[x] = As[k][tm + x];
            #pragma unroll
            for (int y = 0; y < RN; ++y) rw[y] = Ws[k][tn + y];
            #pragma unroll
            for (int x = 0; x < RM; ++x)
                #pragma unroll
                for (int y = 0; y < RN; ++y) acc[x][y] += ra[x] * rw[y];
        }
        __syncthreads();
    }
    #pragma unroll
    for (int x = 0; x < RM; ++x)
        #pragma unroll
        for (int y = 0; y < RN; ++y)
            C[(size_t)(m0 + tm + x) * N + n0 + tn + y] = acc[x][y] + bias[n0 + tn + y];
}

// ctx = [feat | meaning]  grid BL_, block 256
__global__ __launch_bounds__(256) void k_concat(
    const float* __restrict__ feat, const float* __restrict__ meaning,
    float* __restrict__ ctx) {
    int row = blockIdx.x, t = threadIdx.x;
    ctx[(size_t)row * 512 + t] = feat[(size_t)row * DF_ + t];
    ctx[(size_t)row * 512 + 256 + t] = meaning[(size_t)row * DF_ + t];
}

// apply pass-0 update: mu += dmu, alpha *= sigmoid(ctx@agate+b), feat += dffn
__global__ __launch_bounds__(256) void k_apply(
    const float* __restrict__ ctx, const float* __restrict__ agw,
    const float* __restrict__ agb, const float* __restrict__ dmu,
    const float* __restrict__ dffn, float* __restrict__ mu,
    float* __restrict__ alpha, float* __restrict__ feat) {
    __shared__ float red[256];
    int row = blockIdx.x, t = threadIdx.x;
    float c0 = ctx[(size_t)row * 512 + t];
    float c1 = ctx[(size_t)row * 512 + 256 + t];
    float s = block_reduce_sum(c0 * agw[t] + c1 * agw[256 + t], red);
    if (t == 0) alpha[row] *= sigmoidf_(s + agb[0]);
    if (t < DS_) mu[(size_t)row * DS_ + t] += dmu[(size_t)row * DS_ + t];
    feat[(size_t)row * DF_ + t] += dffn[(size_t)row * DF_ + t];
}

// gate + fuse + layernorm.  grid BL_, block 256
__global__ __launch_bounds__(256) void k_fused_ln(
    const float* __restrict__ meaning, const float* __restrict__ blobm,
    const float* __restrict__ tres, const float* __restrict__ bgw,
    const float* __restrict__ bgb, const float* __restrict__ ln_g,
    const float* __restrict__ ln_b, float* __restrict__ hout) {
    __shared__ float red[256];
    int row = blockIdx.x, t = threadIdx.x;
    int b = row >> 10;
    float m = meaning[(size_t)row * DF_ + t];
    float be = blobm[b * DF_ + t];
    float tr = tres[b];
    float gsum = block_reduce_sum(be * bgw[t] + m * bgw[256 + t], red);
    float gate = sigmoidf_(gsum + bgb[0]);
    float f = (1.f - tr) * gate * be + tr * m;
    float mean = block_reduce_sum(f, red) * (1.f / DF_);
    float d = f - mean;
    float var = block_reduce_sum(d * d, red) * (1.f / DF_);
    hout[(size_t)row * DF_ + t] = d * rsqrtf(var + EPS_) * ln_g[t] + ln_b[t];
}

extern "C" void kernel_launch(void* const* d_in, const int* in_sizes, int n_in,
                              void* d_out, int out_size, void* d_ws, size_t ws_size,
                              hipStream_t stream) {
    const int*   tok      = (const int*)d_in[0];
    const float* tok_mu   = (const float*)d_in[1];
    const float* tok_lv   = (const float*)d_in[2];
    const float* tok_ra   = (const float*)d_in[3];
    const float* tok_f    = (const float*)d_in[4];
    const float* pos_mu   = (const float*)d_in[5];
    const float* qproj_w  = (const float*)d_in[6];
    const float* qproj_b  = (const float*)d_in[7];
    const float* hproj_w  = (const float*)d_in[8];
    const float* hproj_b  = (const float*)d_in[9];
    const float* mu_up_w  = (const float*)d_in[10];
    const float* mu_up_b  = (const float*)d_in[11];
    const float* agate_w  = (const float*)d_in[12];
    const float* agate_b  = (const float*)d_in[13];
    const float* ffn_w    = (const float*)d_in[14];
    const float* ffn_b    = (const float*)d_in[15];
    const float* ln_g     = (const float*)d_in[16];
    const float* ln_b     = (const float*)d_in[17];
    const float* lm_w     = (const float*)d_in[18];
    const float* lm_b     = (const float*)d_in[19];
    const float* blob_mu  = (const float*)d_in[20];
    const float* blob_lv  = (const float*)d_in[21];
    const float* blob_ra  = (const float*)d_in[22];
    const float* blob_f   = (const float*)d_in[23];
    const float* bgate_w  = (const float*)d_in[24];
    const float* bgate_b  = (const float*)d_in[25];
    float* out = (float*)d_out;

    float* ws = (float*)d_ws;
    float* mu      = ws;                    // BL*64
    float* iv      = mu + BL_ * DS_;        // BL*64
    float* alpha   = iv + BL_ * DS_;        // BL
    float* feat    = alpha + BL_;           // BL*256
    float* query   = feat + BL_ * DF_;      // B*64
    float* blobm   = query + B_ * DS_;      // B*256
    float* tres    = blobm + B_ * DF_;      // B (pad 64)
    float* q       = tres + 64;             // BL*512
    float* mcat    = q + BL_ * 512;         // BL*2048
    float* meaning = mcat + (size_t)BL_ * 2048; // BL*256
    float* ctx     = meaning + BL_ * DF_;   // BL*512
    float* dmu     = ctx + BL_ * 512;       // BL*64
    float* dffn    = dmu + BL_ * DS_;       // BL*256
    float* hbuf    = dffn + BL_ * DF_;      // BL*256

    k_gather<<<BL_, 256, 0, stream>>>(tok, tok_mu, tok_lv, tok_ra, tok_f, pos_mu,
                                      mu, iv, alpha, feat);
    k_query<<<B_, 256, 0, stream>>>(mu, query);
    k_blob<<<B_, 256, 0, stream>>>(query, blob_mu, blob_lv, blob_ra, blob_f, blobm, tres);

    for (int p = 0; p < 2; ++p) {
        gemm_nt<32, 32, 32, 2, 2><<<dim3(BL_ / 32, 512 / 32), 256, 0, stream>>>(
            mu, qproj_w, qproj_b, q, BL_, 512, DS_);
        k_attn<<<(B_ * H_ * L_) / 4, 256, 0, stream>>>(q, mu, iv, alpha, feat, mcat);
        gemm_nt<32, 32, 32, 2, 2><<<dim3(BL_ / 32, DF_ / 32), 256, 0, stream>>>(
            mcat, hproj_w, hproj_b, meaning, BL_, DF_, H_ * DF_);
        if (p == 0) {
            k_concat<<<BL_, 256, 0, stream>>>(feat, meaning, ctx);
            gemm_nt<32, 32, 32, 2, 2><<<dim3(BL_ / 32, DS_ / 32), 256, 0, stream>>>(
                ctx, mu_up_w, mu_up_b, dmu, BL_, DS_, 512);
            gemm_nt<32, 32, 32, 2, 2><<<dim3(BL_ / 32, DF_ / 32), 256, 0, stream>>>(
                ctx, ffn_w, ffn_b, dffn, BL_, DF_, 512);
            k_apply<<<BL_, 256, 0, stream>>>(ctx, agate_w, agate_b, dmu, dffn,
                                             mu, alpha, feat);
        }
    }

    k_fused_ln<<<BL_, 256, 0, stream>>>(meaning, blobm, tres, bgate_w, bgate_b,
                                        ln_g, ln_b, hbuf);
    gemm_nt<64, 64, 32, 4, 4><<<dim3(BL_ / 64, V_ / 64), 256, 0, stream>>>(
        hbuf, lm_w, lm_b, out, BL_, V_, DF_);
}

// Round 2
// 465.917 us; speedup vs baseline: 1.9123x; 1.9123x over previous
//
#include <hip/hip_runtime.h>
#include <hip/hip_bf16.h>
#include <cstdint>
#include <cstddef>

#define V_   32000
#define DS_  64
#define DF_  256
#define H_   8
#define L_   1024
#define B_   2
#define NB_  512
#define BL_  2048
#define EPS_ 1e-5f

typedef unsigned short ushort_t;
typedef short bf16x8 __attribute__((ext_vector_type(8)));
typedef float f32x4 __attribute__((ext_vector_type(4)));
#define AS1 __attribute__((address_space(1)))
#define AS3 __attribute__((address_space(3)))

__device__ __forceinline__ float sigmoidf_(float x) { return 1.f / (1.f + __expf(-x)); }
__device__ __forceinline__ ushort_t f2bf(float x) {
    __hip_bfloat16 b = __float2bfloat16(x);
    return __builtin_bit_cast(ushort_t, b);
}

__device__ __forceinline__ float block_reduce_sum(float v, float* red) {
    int t = threadIdx.x;
    red[t] = v;
    __syncthreads();
    for (int s = 128; s > 0; s >>= 1) {
        if (t < s) red[t] += red[t + s];
        __syncthreads();
    }
    float r = red[0];
    __syncthreads();
    return r;
}

// f32 -> bf16 convert, 4 elems/thread
__global__ __launch_bounds__(256) void k_cvt(const float* __restrict__ in,
                                             ushort_t* __restrict__ out, int n) {
    int i = (blockIdx.x * 256 + threadIdx.x) * 4;
    if (i >= n) return;
    float4 v = *reinterpret_cast<const float4*>(in + i);
    ushort_t o0 = f2bf(v.x), o1 = f2bf(v.y), o2 = f2bf(v.z), o3 = f2bf(v.w);
    ushort4 o = {o0, o1, o2, o3};
    *reinterpret_cast<ushort4*>(out + i) = o;
}

// ---------------------------------------------------------------------------
__global__ __launch_bounds__(256) void k_gather(
    const int* __restrict__ tok, const float* __restrict__ tok_mu,
    const float* __restrict__ tok_lv, const float* __restrict__ tok_ra,
    const float* __restrict__ tok_f, const float* __restrict__ pos_mu,
    float* __restrict__ mu, float* __restrict__ iv,
    float* __restrict__ alpha, float* __restrict__ feat) {
    int row = blockIdx.x;
    int l = row & (L_ - 1);
    int t = threadIdx.x;
    int v = tok[row];
    if (t < DS_) {
        mu[(size_t)row * DS_ + t] = tok_mu[(size_t)v * DS_ + t] + pos_mu[l * DS_ + t];
        iv[(size_t)row * DS_ + t] = __expf(-tok_lv[(size_t)v * DS_ + t]);
    }
    feat[(size_t)row * DF_ + t] = tok_f[(size_t)v * DF_ + t];
    if (t == 0) alpha[row] = sigmoidf_(tok_ra[v]);
}

__global__ __launch_bounds__(256) void k_query(const float* __restrict__ mu,
                                               float* __restrict__ query) {
    __shared__ float red[256];
    int b = blockIdx.x, t = threadIdx.x;
    int d = t & 63, c = t >> 6;
    float s = 0.f;
    for (int l = c; l < L_; l += 4) s += mu[((size_t)b * L_ + l) * DS_ + d];
    red[t] = s;
    __syncthreads();
    if (c == 0)
        query[b * DS_ + d] = (red[d] + red[64 + d] + red[128 + d] + red[192 + d]) * (1.f / L_);
}

__global__ __launch_bounds__(256) void k_blob(
    const float* __restrict__ query, const float* __restrict__ blob_mu,
    const float* __restrict__ blob_lv, const float* __restrict__ blob_ra,
    const float* __restrict__ blob_f, float* __restrict__ blobm,
    float* __restrict__ tres) {
    __shared__ float sw[NB_];
    __shared__ float sq[DS_];
    int b = blockIdx.x, t = threadIdx.x;
    if (t < DS_) sq[t] = query[b * DS_ + t];
    __syncthreads();
    for (int n = t; n < NB_; n += 256) {
        float d2 = 0.f;
        for (int d = 0; d < DS_; ++d) {
            float diff = sq[d] - blob_mu[n * DS_ + d];
            d2 += __expf(-blob_lv[n * DS_ + d]) * diff * diff;
        }
        sw[n] = sigmoidf_(blob_ra[n]) * __expf(-0.5f * d2);
    }
    __syncthreads();
    if (t == 0) {
        float T = 1.f;
        for (int n = 0; n < NB_; ++n) {
            float a = sw[n];
            sw[n] = a * T;
            T *= (1.f - a);
        }
        tres[b] = T;
    }
    __syncthreads();
    float acc = 0.f;
    for (int n = 0; n < NB_; ++n) acc += sw[n] * blob_f[n * DF_ + t];
    blobm[b * DF_ + t] = acc;
}

// Attention, one wave per (b,h,i), streaming cumprod + early exit; bf16 out.
__global__ __launch_bounds__(256) void k_attn(
    const float* __restrict__ q, const float* __restrict__ mu,
    const float* __restrict__ iv, const float* __restrict__ alpha,
    const float* __restrict__ feat, ushort_t* __restrict__ mcatb) {
    int gtid = blockIdx.x * 256 + threadIdx.x;
    int wid = gtid >> 6;
    int lane = threadIdx.x & 63;
    int b = wid / (H_ * L_);
    int rem = wid % (H_ * L_);
    int h = rem / L_;
    int i = rem % L_;

    float qd = q[((size_t)(b * L_ + i)) * (H_ * DS_) + h * DS_ + lane];
    const float* mub = mu + (size_t)b * L_ * DS_;
    const float* ivb = iv + (size_t)b * L_ * DS_;
    const float* ab  = alpha + b * L_;
    const float* fb  = feat + (size_t)b * L_ * DF_;

    float a0 = 0.f, a1 = 0.f, a2 = 0.f, a3 = 0.f;
    float T = 1.f;
    for (int j = 0; j <= i; ++j) {
        float diff = qd - mub[(size_t)j * DS_ + lane];
        float e = ivb[(size_t)j * DS_ + lane] * diff * diff;
        #pragma unroll
        for (int s = 1; s < 64; s <<= 1) e += __shfl_xor(e, s, 64);
        float a = ab[j] * __expf(-0.5f * e);
        float w = a * T;
        T *= (1.f - a);
        const float* fr = fb + (size_t)j * DF_;
        a0 += w * fr[lane];
        a1 += w * fr[lane + 64];
        a2 += w * fr[lane + 128];
        a3 += w * fr[lane + 192];
        if (T < 1e-12f) break;
    }
    ushort_t* o = mcatb + ((size_t)(b * L_ + i)) * (H_ * DF_) + h * DF_;
    o[lane] = f2bf(a0); o[lane + 64] = f2bf(a1);
    o[lane + 128] = f2bf(a2); o[lane + 192] = f2bf(a3);
}

// ---------------------------------------------------------------------------
// bf16 MFMA GEMM: C(M,N) = A(M,K)bf16 @ W(N,K)bf16^T + bias.  BK=32.
// 256 threads = 4 waves arranged WGM x WGN; per-wave tile (BM/WGM)x(BN/WGN).
template <int BM, int BN, int WGM, int WGN>
__global__ __launch_bounds__(256) void gemm_mfma_bt(
    const ushort_t* __restrict__ A, const ushort_t* __restrict__ W,
    const float* __restrict__ bias, float* __restrict__ C,
    int M, int N, int K) {
    constexpr int WMF = BM / WGM / 16;   // 16x16 frags per wave in M
    constexpr int WNF = BN / WGN / 16;
    __shared__ ushort_t As[BM * 32];
    __shared__ ushort_t Bs[BN * 32];
    const int tid = threadIdx.x;
    const int wave = tid >> 6, lane = tid & 63;
    const int m0 = blockIdx.x * BM, n0 = blockIdx.y * BN;
    const int wr = wave / WGN, wc = wave % WGN;
    const int lr = lane & 15;            // fragment row within 16
    const int lk = (lane >> 4) * 8;      // k offset within 32

    f32x4 acc[WMF][WNF] = {};

    for (int k0 = 0; k0 < K; k0 += 32) {
        // stage A tile (BM x 32) and B tile (BN x 32) via global_load_lds x16B
        #pragma unroll
        for (int it = 0; it < BM / 64; ++it) {
            int cbase = it * 256 + wave * 64;        // 16B-chunk base (uniform/wave)
            int c = cbase + lane;
            int r = c >> 2, cc = c & 3;
            const ushort_t* gp = A + (size_t)(m0 + r) * K + k0 + cc * 8;
            __builtin_amdgcn_global_load_lds((const AS1 unsigned int*)gp,
                                             (AS3 unsigned int*)&As[cbase * 8], 16, 0, 0);
        }
        #pragma unroll
        for (int it = 0; it < BN / 64; ++it) {
            int cbase = it * 256 + wave * 64;
            int c = cbase + lane;
            int r = c >> 2, cc = c & 3;
            const ushort_t* gp = W + (size_t)(n0 + r) * K + k0 + cc * 8;
            __builtin_amdgcn_global_load_lds((const AS1 unsigned int*)gp,
                                             (AS3 unsigned int*)&Bs[cbase * 8], 16, 0, 0);
        }
        __syncthreads();
        bf16x8 af[WMF], bfr[WNF];
        #pragma unroll
        for (int mi = 0; mi < WMF; ++mi)
            af[mi] = *reinterpret_cast<const bf16x8*>(
                &As[(wr * (BM / WGM) + mi * 16 + lr) * 32 + lk]);
        #pragma unroll
        for (int ni = 0; ni < WNF; ++ni)
            bfr[ni] = *reinterpret_cast<const bf16x8*>(
                &Bs[(wc * (BN / WGN) + ni * 16 + lr) * 32 + lk]);
        #pragma unroll
        for (int mi = 0; mi < WMF; ++mi)
            #pragma unroll
            for (int ni = 0; ni < WNF; ++ni)
                acc[mi][ni] = __builtin_amdgcn_mfma_f32_16x16x32_bf16(
                    af[mi], bfr[ni], acc[mi][ni], 0, 0, 0);
        __syncthreads();
    }
    // epilogue: D row = (lane>>4)*4 + j, col = lane&15   [m89/m91 mapping]
    #pragma unroll
    for (int mi = 0; mi < WMF; ++mi)
        #pragma unroll
        for (int ni = 0; ni < WNF; ++ni) {
            int col = n0 + wc * (BN / WGN) + ni * 16 + lr;
            float bv = bias[col];
            #pragma unroll
            for (int j = 0; j < 4; ++j) {
                int row = m0 + wr * (BM / WGM) + mi * 16 + (lane >> 4) * 4 + j;
                C[(size_t)row * N + col] = acc[mi][ni][j] + bv;
            }
        }
}

// ---------------------------------------------------------------------------
// fp32 tiled GEMM (small GEMMs): C(M,N) = A(M,K) @ W(N,K)^T + bias
template <int TM, int TN, int TK, int RM, int RN>
__global__ __launch_bounds__(256) void gemm_nt(
    const float* __restrict__ A, const float* __restrict__ W,
    const float* __restrict__ bias, float* __restrict__ C,
    int M, int N, int K) {
    __shared__ float As[TK][TM + 4];
    __shared__ float Ws[TK][TN + 4];
    const int tid = threadIdx.x;
    const int m0 = blockIdx.x * TM;
    const int n0 = blockIdx.y * TN;
    constexpr int TX = TN / RN;
    const int tm = (tid / TX) * RM;
    const int tn = (tid % TX) * RN;
    float acc[RM][RN] = {};

    for (int k0 = 0; k0 < K; k0 += TK) {
        constexpr int AE = TM * TK / 256;
        #pragma unroll
        for (int e = 0; e < AE; e += 4) {
            int idx = tid * AE + e;
            int r = idx / TK, c = idx % TK;
            const float4 v = *reinterpret_cast<const float4*>(&A[(size_t)(m0 + r) * K + k0 + c]);
            As[c][r] = v.x; As[c + 1][r] = v.y; As[c + 2][r] = v.z; As[c + 3][r] = v.w;
        }
        constexpr int WE = TN * TK / 256;
        #pragma unroll
        for (int e = 0; e < WE; e += 4) {
            int idx = tid * WE + e;
            int r = idx / TK, c = idx % TK;
            const float4 v = *reinterpret_cast<const float4*>(&W[(size_t)(n0 + r) * K + k0 + c]);
            Ws[c][r] = v.x; Ws[c + 1][r] = v.y; Ws[c + 2][r] = v.z; Ws[c + 3][r] = v.w;
        }
        __syncthreads();
        #pragma unroll
        for (int k = 0; k < TK; ++k) {
            float ra[RM], rw[RN];
            #pragma unroll
            for (int x = 0; x < RM; ++x) ra[x] = As[k][tm + x];
            #pragma unroll
            for (int y = 0; y < RN; ++y) rw[y] = Ws[k][tn + y];
            #pragma unroll
            for (int x = 0; x < RM; ++x)
                #pragma unroll
                for (int y = 0; y < RN; ++y) acc[x][y] += ra[x] * rw[y];
        }
        __syncthreads();
    }
    #pragma unroll
    for (int x = 0; x < RM; ++x)
        #pragma unroll
        for (int y = 0; y < RN; ++y)
            C[(size_t)(m0 + tm + x) * N + n0 + tn + y] = acc[x][y] + bias[n0 + tn + y];
}

__global__ __launch_bounds__(256) void k_concat(
    const float* __restrict__ feat, const float* __restrict__ meaning,
    float* __restrict__ ctx) {
    int row = blockIdx.x, t = threadIdx.x;
    ctx[(size_t)row * 512 + t] = feat[(size_t)row * DF_ + t];
    ctx[(size_t)row * 512 + 256 + t] = meaning[(size_t)row * DF_ + t];
}

__global__ __launch_bounds__(256) void k_apply(
    const float* __restrict__ ctx, const float* __restrict__ agw,
    const float* __restrict__ agb, const float* __restrict__ dmu,
    const float* __restrict__ dffn, float* __restrict__ mu,
    float* __restrict__ alpha, float* __restrict__ feat) {
    __shared__ float red[256];
    int row = blockIdx.x, t = threadIdx.x;
    float c0 = ctx[(size_t)row * 512 + t];
    float c1 = ctx[(size_t)row * 512 + 256 + t];
    float s = block_reduce_sum(c0 * agw[t] + c1 * agw[256 + t], red);
    if (t == 0) alpha[row] *= sigmoidf_(s + agb[0]);
    if (t < DS_) mu[(size_t)row * DS_ + t] += dmu[(size_t)row * DS_ + t];
    feat[(size_t)row * DF_ + t] += dffn[(size_t)row * DF_ + t];
}

// gate + fuse + layernorm -> bf16 h
__global__ __launch_bounds__(256) void k_fused_ln(
    const float* __restrict__ meaning, const float* __restrict__ blobm,
    const float* __restrict__ tres, const float* __restrict__ bgw,
    const float* __restrict__ bgb, const float* __restrict__ ln_g,
    const float* __restrict__ ln_b, ushort_t* __restrict__ houtb) {
    __shared__ float red[256];
    int row = blockIdx.x, t = threadIdx.x;
    int b = row >> 10;
    float m = meaning[(size_t)row * DF_ + t];
    float be = blobm[b * DF_ + t];
    float tr = tres[b];
    float gsum = block_reduce_sum(be * bgw[t] + m * bgw[256 + t], red);
    float gate = sigmoidf_(gsum + bgb[0]);
    float f = (1.f - tr) * gate * be + tr * m;
    float mean = block_reduce_sum(f, red) * (1.f / DF_);
    float d = f - mean;
    float var = block_reduce_sum(d * d, red) * (1.f / DF_);
    houtb[(size_t)row * DF_ + t] = f2bf(d * rsqrtf(var + EPS_) * ln_g[t] + ln_b[t]);
}

extern "C" void kernel_launch(void* const* d_in, const int* in_sizes, int n_in,
                              void* d_out, int out_size, void* d_ws, size_t ws_size,
                              hipStream_t stream) {
    const int*   tok      = (const int*)d_in[0];
    const float* tok_mu   = (const float*)d_in[1];
    const float* tok_lv   = (const float*)d_in[2];
    const float* tok_ra   = (const float*)d_in[3];
    const float* tok_f    = (const float*)d_in[4];
    const float* pos_mu   = (const float*)d_in[5];
    const float* qproj_w  = (const float*)d_in[6];
    const float* qproj_b  = (const float*)d_in[7];
    const float* hproj_w  = (const float*)d_in[8];
    const float* hproj_b  = (const float*)d_in[9];
    const float* mu_up_w  = (const float*)d_in[10];
    const float* mu_up_b  = (const float*)d_in[11];
    const float* agate_w  = (const float*)d_in[12];
    const float* agate_b  = (const float*)d_in[13];
    const float* ffn_w    = (const float*)d_in[14];
    const float* ffn_b    = (const float*)d_in[15];
    const float* ln_g     = (const float*)d_in[16];
    const float* ln_b     = (const float*)d_in[17];
    const float* lm_w     = (const float*)d_in[18];
    const float* lm_b     = (const float*)d_in[19];
    const float* blob_mu  = (const float*)d_in[20];
    const float* blob_lv  = (const float*)d_in[21];
    const float* blob_ra  = (const float*)d_in[22];
    const float* blob_f   = (const float*)d_in[23];
    const float* bgate_w  = (const float*)d_in[24];
    const float* bgate_b  = (const float*)d_in[25];
    float* out = (float*)d_out;

    float* ws = (float*)d_ws;
    float* mu      = ws;                        // BL*64
    float* iv      = mu + BL_ * DS_;            // BL*64
    float* alpha   = iv + BL_ * DS_;            // BL
    float* feat    = alpha + BL_;               // BL*256
    float* query   = feat + BL_ * DF_;          // B*64
    float* blobm   = query + B_ * DS_;          // B*256
    float* tres    = blobm + B_ * DF_;          // pad 64
    float* q       = tres + 64;                 // BL*512
    float* meaning = q + BL_ * 512;             // BL*256
    float* ctx     = meaning + BL_ * DF_;       // BL*512
    float* dmu     = ctx + BL_ * 512;           // BL*64
    float* dffn    = dmu + BL_ * DS_;           // BL*256
    ushort_t* mcatb = (ushort_t*)(dffn + BL_ * DF_);      // BL*2048 bf16
    ushort_t* hbufb = mcatb + (size_t)BL_ * 2048;         // BL*256 bf16
    ushort_t* wbf   = hbufb + (size_t)BL_ * DF_;          // V*256 bf16
    ushort_t* hpwbf = wbf + (size_t)V_ * DF_;             // 256*2048 bf16

    // one-shot weight converts (stream-ordered, deterministic)
    k_cvt<<<(V_ * DF_) / 1024, 256, 0, stream>>>(lm_w, wbf, V_ * DF_);
    k_cvt<<<(DF_ * 2048) / 1024, 256, 0, stream>>>(hproj_w, hpwbf, DF_ * 2048);

    k_gather<<<BL_, 256, 0, stream>>>(tok, tok_mu, tok_lv, tok_ra, tok_f, pos_mu,
                                      mu, iv, alpha, feat);
    k_query<<<B_, 256, 0, stream>>>(mu, query);
    k_blob<<<B_, 256, 0, stream>>>(query, blob_mu, blob_lv, blob_ra, blob_f, blobm, tres);

    for (int p = 0; p < 2; ++p) {
        gemm_nt<32, 32, 32, 2, 2><<<dim3(BL_ / 32, 512 / 32), 256, 0, stream>>>(
            mu, qproj_w, qproj_b, q, BL_, 512, DS_);
        k_attn<<<(B_ * H_ * L_) / 4, 256, 0, stream>>>(q, mu, iv, alpha, feat, mcatb);
        gemm_mfma_bt<64, 64, 2, 2><<<dim3(BL_ / 64, DF_ / 64), 256, 0, stream>>>(
            mcatb, hpwbf, hproj_b, meaning, BL_, DF_, H_ * DF_);
        if (p == 0) {
            k_concat<<<BL_, 256, 0, stream>>>(feat, meaning, ctx);
            gemm_nt<32, 32, 32, 2, 2><<<dim3(BL_ / 32, DS_ / 32), 256, 0, stream>>>(
                ctx, mu_up_w, mu_up_b, dmu, BL_, DS_, 512);
            gemm_nt<32, 32, 32, 2, 2><<<dim3(BL_ / 32, DF_ / 32), 256, 0, stream>>>(
                ctx, ffn_w, ffn_b, dffn, BL_, DF_, 512);
            k_apply<<<BL_, 256, 0, stream>>>(ctx, agate_w, agate_b, dmu, dffn,
                                             mu, alpha, feat);
        }
    }

    k_fused_ln<<<BL_, 256, 0, stream>>>(meaning, blobm, tres, bgate_w, bgate_b,
                                        ln_g, ln_b, hbufb);
    gemm_mfma_bt<128, 128, 2, 2><<<dim3(BL_ / 128, V_ / 128), 256, 0, stream>>>(
        hbufb, wbf, lm_b, out, BL_, V_, DF_);
}

// Round 4
// 455.464 us; speedup vs baseline: 1.9562x; 1.0230x over previous
//
#include <hip/hip_runtime.h>
#include <hip/hip_bf16.h>
#include <cstdint>
#include <cstddef>

#define V_   32000
#define DS_  64
#define DF_  256
#define H_   8
#define L_   1024
#define B_   2
#define NB_  512
#define BL_  2048
#define EPS_ 1e-5f

typedef unsigned short ushort_t;
typedef short bf16x8 __attribute__((ext_vector_type(8)));
typedef float f32x4 __attribute__((ext_vector_type(4)));
#define AS1 __attribute__((address_space(1)))
#define AS3 __attribute__((address_space(3)))

__device__ __forceinline__ float sigmoidf_(float x) { return 1.f / (1.f + __expf(-x)); }
__device__ __forceinline__ ushort_t f2bf(float x) {
    __hip_bfloat16 b = __float2bfloat16(x);
    return __builtin_bit_cast(ushort_t, b);
}

__device__ __forceinline__ float block_reduce_sum(float v, float* red) {
    int t = threadIdx.x;
    red[t] = v;
    __syncthreads();
    for (int s = 128; s > 0; s >>= 1) {
        if (t < s) red[t] += red[t + s];
        __syncthreads();
    }
    float r = red[0];
    __syncthreads();
    return r;
}

// f32 -> bf16 convert, 4 elems/thread
__global__ __launch_bounds__(256) void k_cvt(const float* __restrict__ in,
                                             ushort_t* __restrict__ out, int n) {
    int i = (blockIdx.x * 256 + threadIdx.x) * 4;
    if (i >= n) return;
    float4 v = *reinterpret_cast<const float4*>(in + i);
    ushort_t o0 = f2bf(v.x), o1 = f2bf(v.y), o2 = f2bf(v.z), o3 = f2bf(v.w);
    ushort4 o = {o0, o1, o2, o3};
    *reinterpret_cast<ushort4*>(out + i) = o;
}

// ---------------------------------------------------------------------------
__global__ __launch_bounds__(256) void k_gather(
    const int* __restrict__ tok, const float* __restrict__ tok_mu,
    const float* __restrict__ tok_lv, const float* __restrict__ tok_ra,
    const float* __restrict__ tok_f, const float* __restrict__ pos_mu,
    float* __restrict__ mu, float* __restrict__ iv,
    float* __restrict__ alpha, float* __restrict__ feat) {
    int row = blockIdx.x;
    int l = row & (L_ - 1);
    int t = threadIdx.x;
    int v = tok[row];
    if (t < DS_) {
        mu[(size_t)row * DS_ + t] = tok_mu[(size_t)v * DS_ + t] + pos_mu[l * DS_ + t];
        iv[(size_t)row * DS_ + t] = __expf(-tok_lv[(size_t)v * DS_ + t]);
    }
    feat[(size_t)row * DF_ + t] = tok_f[(size_t)v * DF_ + t];
    if (t == 0) alpha[row] = sigmoidf_(tok_ra[v]);
}

__global__ __launch_bounds__(256) void k_query(const float* __restrict__ mu,
                                               float* __restrict__ query) {
    __shared__ float red[256];
    int b = blockIdx.x, t = threadIdx.x;
    int d = t & 63, c = t >> 6;
    float s = 0.f;
    for (int l = c; l < L_; l += 4) s += mu[((size_t)b * L_ + l) * DS_ + d];
    red[t] = s;
    __syncthreads();
    if (c == 0)
        query[b * DS_ + d] = (red[d] + red[64 + d] + red[128 + d] + red[192 + d]) * (1.f / L_);
}

// Blob mixture with parallel product-scan (Hillis-Steele over 512).
__global__ __launch_bounds__(256) void k_blob(
    const float* __restrict__ query, const float* __restrict__ blob_mu,
    const float* __restrict__ blob_lv, const float* __restrict__ blob_ra,
    const float* __restrict__ blob_f, float* __restrict__ blobm,
    float* __restrict__ tres) {
    __shared__ float sa[NB_];
    __shared__ float sp[NB_];
    __shared__ float sq[DS_];
    int b = blockIdx.x, t = threadIdx.x;
    if (t < DS_) sq[t] = query[b * DS_ + t];
    __syncthreads();
    for (int n = t; n < NB_; n += 256) {
        float d2 = 0.f;
        for (int d = 0; d < DS_; ++d) {
            float diff = sq[d] - blob_mu[n * DS_ + d];
            d2 += __expf(-blob_lv[n * DS_ + d]) * diff * diff;
        }
        float a = sigmoidf_(blob_ra[n]) * __expf(-0.5f * d2);
        sa[n] = a;
        sp[n] = 1.f - a;
    }
    __syncthreads();
    int n0 = t, n1 = t + 256;
    // inclusive product scan of (1-a)
    for (int s = 1; s < NB_; s <<= 1) {
        float t0 = (n0 >= s) ? sp[n0 - s] : 1.f;
        float t1 = (n1 >= s) ? sp[n1 - s] : 1.f;
        __syncthreads();
        sp[n0] *= t0;
        sp[n1] *= t1;
        __syncthreads();
    }
    float w0 = sa[n0] * (n0 ? sp[n0 - 1] : 1.f);
    float w1 = sa[n1] * sp[n1 - 1];
    __syncthreads();
    sa[n0] = w0;
    sa[n1] = w1;
    if (t == 0) tres[b] = sp[NB_ - 1];
    __syncthreads();
    float acc = 0.f;
    for (int n = 0; n < NB_; ++n) acc += sa[n] * blob_f[n * DF_ + t];
    blobm[b * DF_ + t] = acc;
}

// Attention, one wave per (b,h,i), streaming cumprod + early exit; bf16 out.
__global__ __launch_bounds__(256) void k_attn(
    const float* __restrict__ q, const float* __restrict__ mu,
    const float* __restrict__ iv, const float* __restrict__ alpha,
    const float* __restrict__ feat, ushort_t* __restrict__ mcatb) {
    int gtid = blockIdx.x * 256 + threadIdx.x;
    int wid = gtid >> 6;
    int lane = threadIdx.x & 63;
    int b = wid / (H_ * L_);
    int rem = wid % (H_ * L_);
    int h = rem / L_;
    int i = rem % L_;

    float qd = q[((size_t)(b * L_ + i)) * (H_ * DS_) + h * DS_ + lane];
    const float* mub = mu + (size_t)b * L_ * DS_;
    const float* ivb = iv + (size_t)b * L_ * DS_;
    const float* ab  = alpha + b * L_;
    const float* fb  = feat + (size_t)b * L_ * DF_;

    float a0 = 0.f, a1 = 0.f, a2 = 0.f, a3 = 0.f;
    float T = 1.f;
    for (int j = 0; j <= i; ++j) {
        float diff = qd - mub[(size_t)j * DS_ + lane];
        float e = ivb[(size_t)j * DS_ + lane] * diff * diff;
        #pragma unroll
        for (int s = 1; s < 64; s <<= 1) e += __shfl_xor(e, s, 64);
        float a = ab[j] * __expf(-0.5f * e);
        float w = a * T;
        T *= (1.f - a);
        const float* fr = fb + (size_t)j * DF_;
        a0 += w * fr[lane];
        a1 += w * fr[lane + 64];
        a2 += w * fr[lane + 128];
        a3 += w * fr[lane + 192];
        if (T < 1e-12f) break;
    }
    ushort_t* o = mcatb + ((size_t)(b * L_ + i)) * (H_ * DF_) + h * DF_;
    o[lane] = f2bf(a0); o[lane + 64] = f2bf(a1);
    o[lane + 128] = f2bf(a2); o[lane + 192] = f2bf(a3);
}

// ---------------------------------------------------------------------------
// bf16 MFMA GEMM v2: C(M,N) = A(M,K)bf16 @ W(N,K)^T + bias.
// 2-phase double-buffered staging; chunk-major LDS (conflict-free ds_read_b128);
// LDS-transposed epilogue with coalesced f32x4 (optionally nontemporal) stores.
// 256 threads = 4 waves (WGM x WGN).
template <int BM, int BN, int BK, int WGM, int WGN, bool NTS>
__global__ __launch_bounds__(256) void gemm_mfma2(
    const ushort_t* __restrict__ A, const ushort_t* __restrict__ W,
    const float* __restrict__ bias, float* __restrict__ C,
    int M, int N, int K) {
    constexpr int WMF = BM / WGM / 16;
    constexpr int WNF = BN / WGN / 16;
    constexpr int KK  = BK / 32;
    constexpr int AHALF = BM * BK;            // ushorts per A buffer
    constexpr int BHALF = BN * BK;
    constexpr int STAGE_B = 2 * (AHALF + BHALF) * 2;
    constexpr int EPI_B = BM * BN * 4;
    constexpr int SMEM_B = STAGE_B > EPI_B ? STAGE_B : EPI_B;
    __shared__ __align__(16) char smem[SMEM_B];
    ushort_t* As = (ushort_t*)smem;                      // [2][AHALF]
    ushort_t* Bs = (ushort_t*)(smem + 2 * AHALF * 2);    // [2][BHALF]

    const int tid = threadIdx.x;
    const int wave = tid >> 6, lane = tid & 63;
    const int m0 = blockIdx.x * BM, n0 = blockIdx.y * BN;
    const int wr = wave / WGN, wc = wave % WGN;
    const int lr = lane & 15;
    const int q4 = lane >> 4;

    f32x4 acc[WMF][WNF] = {};

    auto stage = [&](int buf, int t) {
        const int k0 = t * BK;
        ushort_t* Ad = As + buf * AHALF;
        #pragma unroll
        for (int it = 0; it < (BM * BK / 8) / 256; ++it) {
            int cbase = it * 256 + wave * 64;
            int c = cbase + lane;
            int r = c & (BM - 1), c8 = c / BM;   // chunk-major: slot = c8*BM + r
            const ushort_t* gp = A + (size_t)(m0 + r) * K + k0 + c8 * 8;
            __builtin_amdgcn_global_load_lds((const AS1 unsigned int*)gp,
                                             (AS3 unsigned int*)(Ad + cbase * 8), 16, 0, 0);
        }
        ushort_t* Bd = Bs + buf * BHALF;
        #pragma unroll
        for (int it = 0; it < (BN * BK / 8) / 256; ++it) {
            int cbase = it * 256 + wave * 64;
            int c = cbase + lane;
            int r = c & (BN - 1), c8 = c / BN;
            const ushort_t* gp = W + (size_t)(n0 + r) * K + k0 + c8 * 8;
            __builtin_amdgcn_global_load_lds((const AS1 unsigned int*)gp,
                                             (AS3 unsigned int*)(Bd + cbase * 8), 16, 0, 0);
        }
    };

    const int nsteps = K / BK;
    stage(0, 0);
    __syncthreads();
    for (int t = 0; t < nsteps; ++t) {
        const int cur = t & 1;
        if (t + 1 < nsteps) stage(cur ^ 1, t + 1);
        const ushort_t* Ab = As + cur * AHALF;
        const ushort_t* Bb = Bs + cur * BHALF;
        bf16x8 af[WMF][KK], bfr[WNF][KK];
        #pragma unroll
        for (int mi = 0; mi < WMF; ++mi)
            #pragma unroll
            for (int kk = 0; kk < KK; ++kk)
                af[mi][kk] = *reinterpret_cast<const bf16x8*>(
                    &Ab[((kk * 4 + q4) * BM + wr * (BM / WGM) + mi * 16 + lr) * 8]);
        #pragma unroll
        for (int ni = 0; ni < WNF; ++ni)
            #pragma unroll
            for (int kk = 0; kk < KK; ++kk)
                bfr[ni][kk] = *reinterpret_cast<const bf16x8*>(
                    &Bb[((kk * 4 + q4) * BN + wc * (BN / WGN) + ni * 16 + lr) * 8]);
        #pragma unroll
        for (int kk = 0; kk < KK; ++kk)
            #pragma unroll
            for (int mi = 0; mi < WMF; ++mi)
                #pragma unroll
                for (int ni = 0; ni < WNF; ++ni)
                    acc[mi][ni] = __builtin_amdgcn_mfma_f32_16x16x32_bf16(
                        af[mi][kk], bfr[ni][kk], acc[mi][ni], 0, 0, 0);
        __syncthreads();   // drains vmcnt(0): next-tile stage landed; guards buffers
    }

    // epilogue: acc -> LDS tile (fp32) -> coalesced f32x4 stores
    float* tile = (float*)smem;
    #pragma unroll
    for (int mi = 0; mi < WMF; ++mi)
        #pragma unroll
        for (int ni = 0; ni < WNF; ++ni) {
            int col = wc * (BN / WGN) + ni * 16 + lr;
            float bv = bias[n0 + col];
            #pragma unroll
            for (int j = 0; j < 4; ++j) {
                int row = wr * (BM / WGM) + mi * 16 + q4 * 4 + j;
                tile[row * BN + col] = acc[mi][ni][j] + bv;
            }
        }
    __syncthreads();
    constexpr int EV = (BM * BN / 4) / 256;
    #pragma unroll
    for (int e = 0; e < EV; ++e) {
        int idx = e * 256 + tid;
        int r = idx / (BN / 4), c4 = idx % (BN / 4);
        f32x4 v = reinterpret_cast<const f32x4*>(tile)[idx];
        f32x4* dst = reinterpret_cast<f32x4*>(&C[(size_t)(m0 + r) * N + n0 + c4 * 4]);
        if (NTS) __builtin_nontemporal_store(v, dst);
        else *dst = v;
    }
}

// ---------------------------------------------------------------------------
// fp32 tiled GEMM (small GEMMs): C(M,N) = A(M,K) @ W(N,K)^T + bias
template <int TM, int TN, int TK, int RM, int RN>
__global__ __launch_bounds__(256) void gemm_nt(
    const float* __restrict__ A, const float* __restrict__ W,
    const float* __restrict__ bias, float* __restrict__ C,
    int M, int N, int K) {
    __shared__ float As[TK][TM + 4];
    __shared__ float Ws[TK][TN + 4];
    const int tid = threadIdx.x;
    const int m0 = blockIdx.x * TM;
    const int n0 = blockIdx.y * TN;
    constexpr int TX = TN / RN;
    const int tm = (tid / TX) * RM;
    const int tn = (tid % TX) * RN;
    float acc[RM][RN] = {};

    for (int k0 = 0; k0 < K; k0 += TK) {
        constexpr int AE = TM * TK / 256;
        #pragma unroll
        for (int e = 0; e < AE; e += 4) {
            int idx = tid * AE + e;
            int r = idx / TK, c = idx % TK;
            const float4 v = *reinterpret_cast<const float4*>(&A[(size_t)(m0 + r) * K + k0 + c]);
            As[c][r] = v.x; As[c + 1][r] = v.y; As[c + 2][r] = v.z; As[c + 3][r] = v.w;
        }
        constexpr int WE = TN * TK / 256;
        #pragma unroll
        for (int e = 0; e < WE; e += 4) {
            int idx = tid * WE + e;
            int r = idx / TK, c = idx % TK;
            const float4 v = *reinterpret_cast<const float4*>(&W[(size_t)(n0 + r) * K + k0 + c]);
            Ws[c][r] = v.x; Ws[c + 1][r] = v.y; Ws[c + 2][r] = v.z; Ws[c + 3][r] = v.w;
        }
        __syncthreads();
        #pragma unroll
        for (int k = 0; k < TK; ++k) {
            float ra[RM], rw[RN];
            #pragma unroll
            for (int x = 0; x < RM; ++x) ra[x] = As[k][tm + x];
            #pragma unroll
            for (int y = 0; y < RN; ++y) rw[y] = Ws[k][tn + y];
            #pragma unroll
            for (int x = 0; x < RM; ++x)
                #pragma unroll
                for (int y = 0; y < RN; ++y) acc[x][y] += ra[x] * rw[y];
        }
        __syncthreads();
    }
    #pragma unroll
    for (int x = 0; x < RM; ++x)
        #pragma unroll
        for (int y = 0; y < RN; ++y)
            C[(size_t)(m0 + tm + x) * N + n0 + tn + y] = acc[x][y] + bias[n0 + tn + y];
}

__global__ __launch_bounds__(256) void k_concat(
    const float* __restrict__ feat, const float* __restrict__ meaning,
    float* __restrict__ ctx) {
    int row = blockIdx.x, t = threadIdx.x;
    ctx[(size_t)row * 512 + t] = feat[(size_t)row * DF_ + t];
    ctx[(size_t)row * 512 + 256 + t] = meaning[(size_t)row * DF_ + t];
}

__global__ __launch_bounds__(256) void k_apply(
    const float* __restrict__ ctx, const float* __restrict__ agw,
    const float* __restrict__ agb, const float* __restrict__ dmu,
    const float* __restrict__ dffn, float* __restrict__ mu,
    float* __restrict__ alpha, float* __restrict__ feat) {
    __shared__ float red[256];
    int row = blockIdx.x, t = threadIdx.x;
    float c0 = ctx[(size_t)row * 512 + t];
    float c1 = ctx[(size_t)row * 512 + 256 + t];
    float s = block_reduce_sum(c0 * agw[t] + c1 * agw[256 + t], red);
    if (t == 0) alpha[row] *= sigmoidf_(s + agb[0]);
    if (t < DS_) mu[(size_t)row * DS_ + t] += dmu[(size_t)row * DS_ + t];
    feat[(size_t)row * DF_ + t] += dffn[(size_t)row * DF_ + t];
}

// gate + fuse + layernorm -> bf16 h
__global__ __launch_bounds__(256) void k_fused_ln(
    const float* __restrict__ meaning, const float* __restrict__ blobm,
    const float* __restrict__ tres, const float* __restrict__ bgw,
    const float* __restrict__ bgb, const float* __restrict__ ln_g,
    const float* __restrict__ ln_b, ushort_t* __restrict__ houtb) {
    __shared__ float red[256];
    int row = blockIdx.x, t = threadIdx.x;
    int b = row >> 10;
    float m = meaning[(size_t)row * DF_ + t];
    float be = blobm[b * DF_ + t];
    float tr = tres[b];
    float gsum = block_reduce_sum(be * bgw[t] + m * bgw[256 + t], red);
    float gate = sigmoidf_(gsum + bgb[0]);
    float f = (1.f - tr) * gate * be + tr * m;
    float mean = block_reduce_sum(f, red) * (1.f / DF_);
    float d = f - mean;
    float var = block_reduce_sum(d * d, red) * (1.f / DF_);
    houtb[(size_t)row * DF_ + t] = f2bf(d * rsqrtf(var + EPS_) * ln_g[t] + ln_b[t]);
}

extern "C" void kernel_launch(void* const* d_in, const int* in_sizes, int n_in,
                              void* d_out, int out_size, void* d_ws, size_t ws_size,
                              hipStream_t stream) {
    const int*   tok      = (const int*)d_in[0];
    const float* tok_mu   = (const float*)d_in[1];
    const float* tok_lv   = (const float*)d_in[2];
    const float* tok_ra   = (const float*)d_in[3];
    const float* tok_f    = (const float*)d_in[4];
    const float* pos_mu   = (const float*)d_in[5];
    const float* qproj_w  = (const float*)d_in[6];
    const float* qproj_b  = (const float*)d_in[7];
    const float* hproj_w  = (const float*)d_in[8];
    const float* hproj_b  = (const float*)d_in[9];
    const float* mu_up_w  = (const float*)d_in[10];
    const float* mu_up_b  = (const float*)d_in[11];
    const float* agate_w  = (const float*)d_in[12];
    const float* agate_b  = (const float*)d_in[13];
    const float* ffn_w    = (const float*)d_in[14];
    const float* ffn_b    = (const float*)d_in[15];
    const float* ln_g     = (const float*)d_in[16];
    const float* ln_b     = (const float*)d_in[17];
    const float* lm_w     = (const float*)d_in[18];
    const float* lm_b     = (const float*)d_in[19];
    const float* blob_mu  = (const float*)d_in[20];
    const float* blob_lv  = (const float*)d_in[21];
    const float* blob_ra  = (const float*)d_in[22];
    const float* blob_f   = (const float*)d_in[23];
    const float* bgate_w  = (const float*)d_in[24];
    const float* bgate_b  = (const float*)d_in[25];
    float* out = (float*)d_out;

    float* ws = (float*)d_ws;
    float* mu      = ws;                        // BL*64
    float* iv      = mu + BL_ * DS_;            // BL*64
    float* alpha   = iv + BL_ * DS_;            // BL
    float* feat    = alpha + BL_;               // BL*256
    float* query   = feat + BL_ * DF_;          // B*64
    float* blobm   = query + B_ * DS_;          // B*256
    float* tres    = blobm + B_ * DF_;          // pad 64
    float* q       = tres + 64;                 // BL*512
    float* meaning = q + BL_ * 512;             // BL*256
    float* ctx     = meaning + BL_ * DF_;       // BL*512
    float* dmu     = ctx + BL_ * 512;           // BL*64
    float* dffn    = dmu + BL_ * DS_;           // BL*256
    ushort_t* mcatb = (ushort_t*)(dffn + BL_ * DF_);      // BL*2048 bf16
    ushort_t* hbufb = mcatb + (size_t)BL_ * 2048;         // BL*256 bf16
    ushort_t* wbf   = hbufb + (size_t)BL_ * DF_;          // V*256 bf16
    ushort_t* hpwbf = wbf + (size_t)V_ * DF_;             // 256*2048 bf16

    // one-shot weight converts (stream-ordered, deterministic)
    k_cvt<<<(V_ * DF_) / 1024, 256, 0, stream>>>(lm_w, wbf, V_ * DF_);
    k_cvt<<<(DF_ * 2048) / 1024, 256, 0, stream>>>(hproj_w, hpwbf, DF_ * 2048);

    k_gather<<<BL_, 256, 0, stream>>>(tok, tok_mu, tok_lv, tok_ra, tok_f, pos_mu,
                                      mu, iv, alpha, feat);
    k_query<<<B_, 256, 0, stream>>>(mu, query);
    k_blob<<<B_, 256, 0, stream>>>(query, blob_mu, blob_lv, blob_ra, blob_f, blobm, tres);

    for (int p = 0; p < 2; ++p) {
        gemm_nt<32, 32, 32, 2, 2><<<dim3(BL_ / 32, 512 / 32), 256, 0, stream>>>(
            mu, qproj_w, qproj_b, q, BL_, 512, DS_);
        k_attn<<<(B_ * H_ * L_) / 4, 256, 0, stream>>>(q, mu, iv, alpha, feat, mcatb);
        gemm_mfma2<32, 32, 64, 2, 2, false><<<dim3(BL_ / 32, DF_ / 32), 256, 0, stream>>>(
            mcatb, hpwbf, hproj_b, meaning, BL_, DF_, H_ * DF_);
        if (p == 0) {
            k_concat<<<BL_, 256, 0, stream>>>(feat, meaning, ctx);
            gemm_nt<32, 32, 32, 2, 2><<<dim3(BL_ / 32, DS_ / 32), 256, 0, stream>>>(
                ctx, mu_up_w, mu_up_b, dmu, BL_, DS_, 512);
            gemm_nt<32, 32, 32, 2, 2><<<dim3(BL_ / 32, DF_ / 32), 256, 0, stream>>>(
                ctx, ffn_w, ffn_b, dffn, BL_, DF_, 512);
            k_apply<<<BL_, 256, 0, stream>>>(ctx, agate_w, agate_b, dmu, dffn,
                                             mu, alpha, feat);
        }
    }

    k_fused_ln<<<BL_, 256, 0, stream>>>(meaning, blobm, tres, bgate_w, bgate_b,
                                        ln_g, ln_b, hbufb);
    gemm_mfma2<128, 128, 64, 2, 2, true><<<dim3(BL_ / 128, V_ / 128), 256, 0, stream>>>(
        hbufb, wbf, lm_b, out, BL_, V_, DF_);
}

// Round 5
// 392.036 us; speedup vs baseline: 2.2727x; 1.1618x over previous
//
#include <hip/hip_runtime.h>
#include <hip/hip_bf16.h>
#include <cstdint>
#include <cstddef>

#define V_   32000
#define DS_  64
#define DF_  256
#define H_   8
#define L_   1024
#define B_   2
#define NB_  512
#define BL_  2048
#define EPS_ 1e-5f

typedef unsigned short ushort_t;
typedef short bf16x8 __attribute__((ext_vector_type(8)));
typedef float f32x4 __attribute__((ext_vector_type(4)));
#define AS1 __attribute__((address_space(1)))
#define AS3 __attribute__((address_space(3)))

__device__ __forceinline__ float sigmoidf_(float x) { return 1.f / (1.f + __expf(-x)); }
__device__ __forceinline__ ushort_t f2bf(float x) {
    __hip_bfloat16 b = __float2bfloat16(x);
    return __builtin_bit_cast(ushort_t, b);
}

__device__ __forceinline__ float block_reduce_sum(float v, float* red) {
    int t = threadIdx.x;
    red[t] = v;
    __syncthreads();
    for (int s = 128; s > 0; s >>= 1) {
        if (t < s) red[t] += red[t + s];
        __syncthreads();
    }
    float r = red[0];
    __syncthreads();
    return r;
}

// ---------------------------------------------------------------------------
// One-shot conversion of all five weight matrices to bf16.
// segments: qproj_w 32768 | mu_up_w 32768 | ffn_w 131072 | hproj_w 524288 | lm_w 8192000
__global__ __launch_bounds__(256) void k_cvt5(
    const float* __restrict__ s0, ushort_t* __restrict__ d0,
    const float* __restrict__ s1, ushort_t* __restrict__ d1,
    const float* __restrict__ s2, ushort_t* __restrict__ d2,
    const float* __restrict__ s3, ushort_t* __restrict__ d3,
    const float* __restrict__ s4, ushort_t* __restrict__ d4) {
    int blk = blockIdx.x;
    const float* s; ushort_t* d; int base;
    if (blk < 32)        { s = s0; d = d0; base = blk; }
    else if (blk < 64)   { s = s1; d = d1; base = blk - 32; }
    else if (blk < 192)  { s = s2; d = d2; base = blk - 64; }
    else if (blk < 704)  { s = s3; d = d3; base = blk - 192; }
    else                 { s = s4; d = d4; base = blk - 704; }
    int i = (base * 256 + threadIdx.x) * 4;
    float4 v = *reinterpret_cast<const float4*>(s + i);
    ushort4 o = {f2bf(v.x), f2bf(v.y), f2bf(v.z), f2bf(v.w)};
    *reinterpret_cast<ushort4*>(d + i) = o;
}

// ---------------------------------------------------------------------------
// Gather + transposed layouts. grid BL_, block 256
__global__ __launch_bounds__(256) void k_gather(
    const int* __restrict__ tok, const float* __restrict__ tok_mu,
    const float* __restrict__ tok_lv, const float* __restrict__ tok_ra,
    const float* __restrict__ tok_f, const float* __restrict__ pos_mu,
    float* __restrict__ mu, float* __restrict__ muT, float* __restrict__ ivT,
    ushort_t* __restrict__ mub16, float* __restrict__ alpha,
    float* __restrict__ feat) {
    int row = blockIdx.x;
    int l = row & (L_ - 1);
    int t = threadIdx.x;
    int v = tok[row];
    if (t < DS_) {
        float m = tok_mu[(size_t)v * DS_ + t] + pos_mu[l * DS_ + t];
        mu[(size_t)row * DS_ + t] = m;
        muT[(size_t)t * BL_ + row] = m;
        mub16[(size_t)row * DS_ + t] = f2bf(m);
        ivT[(size_t)t * BL_ + row] = __expf(-tok_lv[(size_t)v * DS_ + t]);
    }
    feat[(size_t)row * DF_ + t] = tok_f[(size_t)v * DF_ + t];
    if (t == 0) alpha[row] = sigmoidf_(tok_ra[v]);
}

// query (mean of mu over L) + blob mixture with parallel product-scan. grid B_
__global__ __launch_bounds__(256) void k_queryblob(
    const float* __restrict__ mu, const float* __restrict__ blob_mu,
    const float* __restrict__ blob_lv, const float* __restrict__ blob_ra,
    const float* __restrict__ blob_f, float* __restrict__ blobm,
    float* __restrict__ tres) {
    __shared__ float red[256];
    __shared__ float sq[DS_];
    __shared__ float sa[NB_];
    __shared__ float sp[NB_];
    int b = blockIdx.x, t = threadIdx.x;
    int d = t & 63, c = t >> 6;
    float s = 0.f;
    for (int l = c; l < L_; l += 4) s += mu[((size_t)b * L_ + l) * DS_ + d];
    red[t] = s;
    __syncthreads();
    if (c == 0)
        sq[d] = (red[d] + red[64 + d] + red[128 + d] + red[192 + d]) * (1.f / L_);
    __syncthreads();
    for (int n = t; n < NB_; n += 256) {
        float d2 = 0.f;
        for (int dd = 0; dd < DS_; ++dd) {
            float diff = sq[dd] - blob_mu[n * DS_ + dd];
            d2 += __expf(-blob_lv[n * DS_ + dd]) * diff * diff;
        }
        float a = sigmoidf_(blob_ra[n]) * __expf(-0.5f * d2);
        sa[n] = a;
        sp[n] = 1.f - a;
    }
    __syncthreads();
    int n0 = t, n1 = t + 256;
    for (int s2 = 1; s2 < NB_; s2 <<= 1) {
        float t0 = (n0 >= s2) ? sp[n0 - s2] : 1.f;
        float t1 = (n1 >= s2) ? sp[n1 - s2] : 1.f;
        __syncthreads();
        sp[n0] *= t0;
        sp[n1] *= t1;
        __syncthreads();
    }
    float w0 = sa[n0] * (n0 ? sp[n0 - 1] : 1.f);
    float w1 = sa[n1] * sp[n1 - 1];
    __syncthreads();
    sa[n0] = w0;
    sa[n1] = w1;
    if (t == 0) tres[b] = sp[NB_ - 1];
    __syncthreads();
    float acc = 0.f;
    for (int n = 0; n < NB_; ++n) acc += sa[n] * blob_f[n * DF_ + t];
    blobm[b * DF_ + t] = acc;
}

// ---------------------------------------------------------------------------
// Chunk-parallel attention: one wave per (b,h,i); 64 j's per chunk.
// lane j computes its own d2 (coalesced via muT/ivT), one wave scan per chunk,
// ballot-cut on the feature accumulate, chunk-level early exit.
__global__ __launch_bounds__(256) void k_attn2(
    const float* __restrict__ q, const float* __restrict__ muT,
    const float* __restrict__ ivT, const float* __restrict__ alpha,
    const float* __restrict__ feat, ushort_t* __restrict__ mcatb) {
    __shared__ float sq[4][DS_];
    __shared__ float swt[4][64];
    int w = threadIdx.x >> 6, lane = threadIdx.x & 63;
    int wid = blockIdx.x * 4 + w;
    int b = wid / (H_ * L_);
    int rem = wid % (H_ * L_);
    int h = rem / L_;
    int i = rem % L_;

    sq[w][lane] = q[((size_t)(b * L_ + i)) * (H_ * DS_) + h * DS_ + lane];
    const float* mT = muT + b * L_;
    const float* vT = ivT + b * L_;
    const float* ab = alpha + b * L_;
    const float* fb = feat + (size_t)b * L_ * DF_;

    float a0 = 0.f, a1 = 0.f, a2 = 0.f, a3 = 0.f;
    float T = 1.f;
    for (int j0 = 0; j0 <= i; j0 += 64) {
        int jj = j0 + lane;
        int jc = jj <= i ? jj : i;          // clamp for safe loads
        float d2 = 0.f;
        #pragma unroll 16
        for (int d = 0; d < DS_; ++d) {
            float m = mT[d * BL_ + jc];
            float ivv = vT[d * BL_ + jc];
            float diff = sq[w][d] - m;
            d2 = fmaf(ivv * diff, diff, d2);
        }
        float a = (jj <= i) ? ab[jc] * __expf(-0.5f * d2) : 0.f;
        float p = 1.f - a;
        #pragma unroll
        for (int s = 1; s < 64; s <<= 1) {
            float tt = __shfl_up(p, s, 64);
            if (lane >= s) p *= tt;
        }
        float Tex = __shfl_up(p, 1, 64);
        if (lane == 0) Tex = 1.f;
        float wgt = a * T * Tex;
        float Tch = __shfl(p, 63, 64);
        swt[w][lane] = wgt;
        unsigned long long dead = __ballot(p < 1e-12f);
        int jn = i - j0 + 1;
        if (jn > 64) jn = 64;
        if (dead) {
            int cut = __builtin_ctzll(dead) + 1;
            if (cut < jn) jn = cut;
        }
        for (int j = 0; j < jn; ++j) {
            float wj = swt[w][j];
            const float* fr = fb + (size_t)(j0 + j) * DF_;
            a0 = fmaf(wj, fr[lane], a0);
            a1 = fmaf(wj, fr[lane + 64], a1);
            a2 = fmaf(wj, fr[lane + 128], a2);
            a3 = fmaf(wj, fr[lane + 192], a3);
        }
        T *= Tch;
        if (T < 1e-12f) break;
    }
    ushort_t* o = mcatb + ((size_t)(b * L_ + i)) * (H_ * DF_) + h * DF_;
    o[lane] = f2bf(a0); o[lane + 64] = f2bf(a1);
    o[lane + 128] = f2bf(a2); o[lane + 192] = f2bf(a3);
}

// ---------------------------------------------------------------------------
// bf16 MFMA GEMM: C(M,N) = A(M,K)bf16 @ W(N,K)^T + bias.
// 2-phase double-buffered global_load_lds staging; chunk-major LDS layout;
// LDS-transposed epilogue with coalesced f32x4 (optionally nontemporal) stores.
template <int BM, int BN, int BK, int WGM, int WGN, bool NTS>
__global__ __launch_bounds__(256) void gemm_mfma2(
    const ushort_t* __restrict__ A, const ushort_t* __restrict__ W,
    const float* __restrict__ bias, float* __restrict__ C,
    int M, int N, int K) {
    constexpr int WMF = BM / WGM / 16;
    constexpr int WNF = BN / WGN / 16;
    constexpr int KK  = BK / 32;
    constexpr int AHALF = BM * BK;
    constexpr int BHALF = BN * BK;
    constexpr int STAGE_B = 2 * (AHALF + BHALF) * 2;
    constexpr int EPI_B = BM * BN * 4;
    constexpr int SMEM_B = STAGE_B > EPI_B ? STAGE_B : EPI_B;
    __shared__ __align__(16) char smem[SMEM_B];
    ushort_t* As = (ushort_t*)smem;
    ushort_t* Bs = (ushort_t*)(smem + 2 * AHALF * 2);

    const int tid = threadIdx.x;
    const int wave = tid >> 6, lane = tid & 63;
    const int m0 = blockIdx.x * BM, n0 = blockIdx.y * BN;
    const int wr = wave / WGN, wc = wave % WGN;
    const int lr = lane & 15;
    const int q4 = lane >> 4;

    f32x4 acc[WMF][WNF] = {};

    auto stage = [&](int buf, int t) {
        const int k0 = t * BK;
        ushort_t* Ad = As + buf * AHALF;
        #pragma unroll
        for (int it = 0; it < (BM * BK / 8) / 256; ++it) {
            int cbase = it * 256 + wave * 64;
            int c = cbase + lane;
            int r = c & (BM - 1), c8 = c / BM;
            const ushort_t* gp = A + (size_t)(m0 + r) * K + k0 + c8 * 8;
            __builtin_amdgcn_global_load_lds((const AS1 unsigned int*)gp,
                                             (AS3 unsigned int*)(Ad + cbase * 8), 16, 0, 0);
        }
        ushort_t* Bd = Bs + buf * BHALF;
        #pragma unroll
        for (int it = 0; it < (BN * BK / 8) / 256; ++it) {
            int cbase = it * 256 + wave * 64;
            int c = cbase + lane;
            int r = c & (BN - 1), c8 = c / BN;
            const ushort_t* gp = W + (size_t)(n0 + r) * K + k0 + c8 * 8;
            __builtin_amdgcn_global_load_lds((const AS1 unsigned int*)gp,
                                             (AS3 unsigned int*)(Bd + cbase * 8), 16, 0, 0);
        }
    };

    const int nsteps = K / BK;
    stage(0, 0);
    __syncthreads();
    for (int t = 0; t < nsteps; ++t) {
        const int cur = t & 1;
        if (t + 1 < nsteps) stage(cur ^ 1, t + 1);
        const ushort_t* Ab = As + cur * AHALF;
        const ushort_t* Bb = Bs + cur * BHALF;
        bf16x8 af[WMF][KK], bfr[WNF][KK];
        #pragma unroll
        for (int mi = 0; mi < WMF; ++mi)
            #pragma unroll
            for (int kk = 0; kk < KK; ++kk)
                af[mi][kk] = *reinterpret_cast<const bf16x8*>(
                    &Ab[((kk * 4 + q4) * BM + wr * (BM / WGM) + mi * 16 + lr) * 8]);
        #pragma unroll
        for (int ni = 0; ni < WNF; ++ni)
            #pragma unroll
            for (int kk = 0; kk < KK; ++kk)
                bfr[ni][kk] = *reinterpret_cast<const bf16x8*>(
                    &Bb[((kk * 4 + q4) * BN + wc * (BN / WGN) + ni * 16 + lr) * 8]);
        #pragma unroll
        for (int kk = 0; kk < KK; ++kk)
            #pragma unroll
            for (int mi = 0; mi < WMF; ++mi)
                #pragma unroll
                for (int ni = 0; ni < WNF; ++ni)
                    acc[mi][ni] = __builtin_amdgcn_mfma_f32_16x16x32_bf16(
                        af[mi][kk], bfr[ni][kk], acc[mi][ni], 0, 0, 0);
        __syncthreads();
    }

    float* tile = (float*)smem;
    #pragma unroll
    for (int mi = 0; mi < WMF; ++mi)
        #pragma unroll
        for (int ni = 0; ni < WNF; ++ni) {
            int col = wc * (BN / WGN) + ni * 16 + lr;
            float bv = bias[n0 + col];
            #pragma unroll
            for (int j = 0; j < 4; ++j) {
                int row = wr * (BM / WGM) + mi * 16 + q4 * 4 + j;
                tile[row * BN + col] = acc[mi][ni][j] + bv;
            }
        }
    __syncthreads();
    constexpr int EV = (BM * BN / 4) / 256;
    #pragma unroll
    for (int e = 0; e < EV; ++e) {
        int idx = e * 256 + tid;
        int r = idx / (BN / 4), c4 = idx % (BN / 4);
        f32x4 v = reinterpret_cast<const f32x4*>(tile)[idx];
        f32x4* dst = reinterpret_cast<f32x4*>(&C[(size_t)(m0 + r) * N + n0 + c4 * 4]);
        if (NTS) __builtin_nontemporal_store(v, dst);
        else *dst = v;
    }
}

// ---------------------------------------------------------------------------
// ctx -> bf16 [feat | meaning].  grid BL_
__global__ __launch_bounds__(256) void k_concat_b16(
    const float* __restrict__ feat, const float* __restrict__ meaning,
    ushort_t* __restrict__ ctxb) {
    int row = blockIdx.x, t = threadIdx.x;
    ctxb[(size_t)row * 512 + t] = f2bf(feat[(size_t)row * DF_ + t]);
    ctxb[(size_t)row * 512 + 256 + t] = f2bf(meaning[(size_t)row * DF_ + t]);
}

// apply pass-0 update; maintains mu, muT, mub16, alpha, feat.  grid BL_
__global__ __launch_bounds__(256) void k_apply(
    const float* __restrict__ meaning, const float* __restrict__ agw,
    const float* __restrict__ agb, const float* __restrict__ dmu,
    const float* __restrict__ dffn, float* __restrict__ mu,
    float* __restrict__ muT, ushort_t* __restrict__ mub16,
    float* __restrict__ alpha, float* __restrict__ feat) {
    __shared__ float red[256];
    int row = blockIdx.x, t = threadIdx.x;
    float c0 = feat[(size_t)row * DF_ + t];
    float c1 = meaning[(size_t)row * DF_ + t];
    float s = block_reduce_sum(c0 * agw[t] + c1 * agw[256 + t], red);
    if (t == 0) alpha[row] *= sigmoidf_(s + agb[0]);
    if (t < DS_) {
        float m = mu[(size_t)row * DS_ + t] + dmu[(size_t)row * DS_ + t];
        mu[(size_t)row * DS_ + t] = m;
        muT[(size_t)t * BL_ + row] = m;
        mub16[(size_t)row * DS_ + t] = f2bf(m);
    }
    feat[(size_t)row * DF_ + t] = c0 + dffn[(size_t)row * DF_ + t];
}

// gate + fuse + layernorm -> bf16 h.  grid BL_
__global__ __launch_bounds__(256) void k_fused_ln(
    const float* __restrict__ meaning, const float* __restrict__ blobm,
    const float* __restrict__ tres, const float* __restrict__ bgw,
    const float* __restrict__ bgb, const float* __restrict__ ln_g,
    const float* __restrict__ ln_b, ushort_t* __restrict__ houtb) {
    __shared__ float red[256];
    int row = blockIdx.x, t = threadIdx.x;
    int b = row >> 10;
    float m = meaning[(size_t)row * DF_ + t];
    float be = blobm[b * DF_ + t];
    float tr = tres[b];
    float gsum = block_reduce_sum(be * bgw[t] + m * bgw[256 + t], red);
    float gate = sigmoidf_(gsum + bgb[0]);
    float f = (1.f - tr) * gate * be + tr * m;
    float mean = block_reduce_sum(f, red) * (1.f / DF_);
    float d = f - mean;
    float var = block_reduce_sum(d * d, red) * (1.f / DF_);
    houtb[(size_t)row * DF_ + t] = f2bf(d * rsqrtf(var + EPS_) * ln_g[t] + ln_b[t]);
}

extern "C" void kernel_launch(void* const* d_in, const int* in_sizes, int n_in,
                              void* d_out, int out_size, void* d_ws, size_t ws_size,
                              hipStream_t stream) {
    const int*   tok      = (const int*)d_in[0];
    const float* tok_mu   = (const float*)d_in[1];
    const float* tok_lv   = (const float*)d_in[2];
    const float* tok_ra   = (const float*)d_in[3];
    const float* tok_f    = (const float*)d_in[4];
    const float* pos_mu   = (const float*)d_in[5];
    const float* qproj_w  = (const float*)d_in[6];
    const float* qproj_b  = (const float*)d_in[7];
    const float* hproj_w  = (const float*)d_in[8];
    const float* hproj_b  = (const float*)d_in[9];
    const float* mu_up_w  = (const float*)d_in[10];
    const float* mu_up_b  = (const float*)d_in[11];
    const float* agate_w  = (const float*)d_in[12];
    const float* agate_b  = (const float*)d_in[13];
    const float* ffn_w    = (const float*)d_in[14];
    const float* ffn_b    = (const float*)d_in[15];
    const float* ln_g     = (const float*)d_in[16];
    const float* ln_b     = (const float*)d_in[17];
    const float* lm_w     = (const float*)d_in[18];
    const float* lm_b     = (const float*)d_in[19];
    const float* blob_mu  = (const float*)d_in[20];
    const float* blob_lv  = (const float*)d_in[21];
    const float* blob_ra  = (const float*)d_in[22];
    const float* blob_f   = (const float*)d_in[23];
    const float* bgate_w  = (const float*)d_in[24];
    const float* bgate_b  = (const float*)d_in[25];
    float* out = (float*)d_out;

    float* ws = (float*)d_ws;
    float* mu      = ws;                        // BL*64
    float* muT     = mu + BL_ * DS_;            // 64*BL
    float* ivT     = muT + BL_ * DS_;           // 64*BL
    float* alpha   = ivT + BL_ * DS_;           // BL
    float* feat    = alpha + BL_;               // BL*256
    float* blobm   = feat + BL_ * DF_;          // B*256
    float* tres    = blobm + B_ * DF_;          // pad 64
    float* q       = tres + 64;                 // BL*512
    float* meaning = q + BL_ * 512;             // BL*256
    float* dmu     = meaning + BL_ * DF_;       // BL*64
    float* dffn    = dmu + BL_ * DS_;           // BL*256
    ushort_t* mub16 = (ushort_t*)(dffn + BL_ * DF_);      // BL*64
    ushort_t* ctxb  = mub16 + (size_t)BL_ * DS_;          // BL*512
    ushort_t* mcatb = ctxb + (size_t)BL_ * 512;           // BL*2048
    ushort_t* hbufb = mcatb + (size_t)BL_ * 2048;         // BL*256
    ushort_t* wbf   = hbufb + (size_t)BL_ * DF_;          // V*256
    ushort_t* hpwbf = wbf + (size_t)V_ * DF_;             // 256*2048
    ushort_t* qpwbf = hpwbf + (size_t)DF_ * 2048;         // 512*64
    ushort_t* muwbf = qpwbf + (size_t)512 * 64;           // 64*512
    ushort_t* ffnwbf = muwbf + (size_t)64 * 512;          // 256*512

    k_cvt5<<<8704, 256, 0, stream>>>(qproj_w, qpwbf, mu_up_w, muwbf,
                                     ffn_w, ffnwbf, hproj_w, hpwbf, lm_w, wbf);

    k_gather<<<BL_, 256, 0, stream>>>(tok, tok_mu, tok_lv, tok_ra, tok_f, pos_mu,
                                      mu, muT, ivT, mub16, alpha, feat);
    k_queryblob<<<B_, 256, 0, stream>>>(mu, blob_mu, blob_lv, blob_ra, blob_f,
                                        blobm, tres);

    for (int p = 0; p < 2; ++p) {
        gemm_mfma2<32, 32, 64, 2, 2, false><<<dim3(BL_ / 32, 512 / 32), 256, 0, stream>>>(
            mub16, qpwbf, qproj_b, q, BL_, 512, DS_);
        k_attn2<<<(B_ * H_ * L_) / 4, 256, 0, stream>>>(q, muT, ivT, alpha, feat, mcatb);
        gemm_mfma2<32, 32, 64, 2, 2, false><<<dim3(BL_ / 32, DF_ / 32), 256, 0, stream>>>(
            mcatb, hpwbf, hproj_b, meaning, BL_, DF_, H_ * DF_);
        if (p == 0) {
            k_concat_b16<<<BL_, 256, 0, stream>>>(feat, meaning, ctxb);
            gemm_mfma2<32, 32, 64, 2, 2, false><<<dim3(BL_ / 32, DS_ / 32), 256, 0, stream>>>(
                ctxb, muwbf, mu_up_b, dmu, BL_, DS_, 512);
            gemm_mfma2<32, 32, 64, 2, 2, false><<<dim3(BL_ / 32, DF_ / 32), 256, 0, stream>>>(
                ctxb, ffnwbf, ffn_b, dffn, BL_, DF_, 512);
            k_apply<<<BL_, 256, 0, stream>>>(meaning, agate_w, agate_b, dmu, dffn,
                                             mu, muT, mub16, alpha, feat);
        }
    }

    k_fused_ln<<<BL_, 256, 0, stream>>>(meaning, blobm, tres, bgate_w, bgate_b,
                                        ln_g, ln_b, hbufb);
    gemm_mfma2<128, 128, 64, 2, 2, true><<<dim3(BL_ / 128, V_ / 128), 256, 0, stream>>>(
        hbufb, wbf, lm_b, out, BL_, V_, DF_);
}

// Round 6
// 332.437 us; speedup vs baseline: 2.6802x; 1.1793x over previous
//
#include <hip/hip_runtime.h>
#include <hip/hip_bf16.h>
#include <cstdint>
#include <cstddef>

#define V_   32000
#define DS_  64
#define DF_  256
#define H_   8
#define L_   1024
#define B_   2
#define NB_  512
#define BL_  2048
#define EPS_ 1e-5f

typedef unsigned short ushort_t;
typedef unsigned int uint_t;
typedef short bf16x8 __attribute__((ext_vector_type(8)));
typedef float f32x4 __attribute__((ext_vector_type(4)));
#define AS1 __attribute__((address_space(1)))
#define AS3 __attribute__((address_space(3)))

__device__ __forceinline__ float sigmoidf_(float x) { return 1.f / (1.f + __expf(-x)); }
__device__ __forceinline__ ushort_t f2bf(float x) {
    __hip_bfloat16 b = __float2bfloat16(x);
    return __builtin_bit_cast(ushort_t, b);
}
__device__ __forceinline__ uint_t packbf(float lo, float hi) {
    return ((uint_t)f2bf(hi) << 16) | (uint_t)f2bf(lo);
}
__device__ __forceinline__ float bflo(uint_t v) {
    return __builtin_bit_cast(float, v << 16);
}
__device__ __forceinline__ float bfhi(uint_t v) {
    return __builtin_bit_cast(float, v & 0xFFFF0000u);
}

__device__ __forceinline__ float block_reduce_sum(float v, float* red) {
    int t = threadIdx.x;
    red[t] = v;
    __syncthreads();
    for (int s = 128; s > 0; s >>= 1) {
        if (t < s) red[t] += red[t + s];
        __syncthreads();
    }
    float r = red[0];
    __syncthreads();
    return r;
}

// ---------------------------------------------------------------------------
// One-shot conversion of all five weight matrices to bf16.
__global__ __launch_bounds__(256) void k_cvt5(
    const float* __restrict__ s0, ushort_t* __restrict__ d0,
    const float* __restrict__ s1, ushort_t* __restrict__ d1,
    const float* __restrict__ s2, ushort_t* __restrict__ d2,
    const float* __restrict__ s3, ushort_t* __restrict__ d3,
    const float* __restrict__ s4, ushort_t* __restrict__ d4) {
    int blk = blockIdx.x;
    const float* s; ushort_t* d; int base;
    if (blk < 32)        { s = s0; d = d0; base = blk; }
    else if (blk < 64)   { s = s1; d = d1; base = blk - 32; }
    else if (blk < 192)  { s = s2; d = d2; base = blk - 64; }
    else if (blk < 704)  { s = s3; d = d3; base = blk - 192; }
    else                 { s = s4; d = d4; base = blk - 704; }
    int i = (base * 256 + threadIdx.x) * 4;
    float4 v = *reinterpret_cast<const float4*>(s + i);
    ushort4 o = {f2bf(v.x), f2bf(v.y), f2bf(v.z), f2bf(v.w)};
    *reinterpret_cast<ushort4*>(d + i) = o;
}

// ---------------------------------------------------------------------------
// Gather. Writes: mu (f32), mub16, muivP (packed bf16 mu|iv, d-major),
// feat (f32), featb16, featP (packed quadrant pairs), alpha.
__global__ __launch_bounds__(256) void k_gather(
    const int* __restrict__ tok, const float* __restrict__ tok_mu,
    const float* __restrict__ tok_lv, const float* __restrict__ tok_ra,
    const float* __restrict__ tok_f, const float* __restrict__ pos_mu,
    float* __restrict__ mu, ushort_t* __restrict__ mub16,
    uint_t* __restrict__ muivP, float* __restrict__ alpha,
    float* __restrict__ feat, ushort_t* __restrict__ featb16,
    uint_t* __restrict__ featP) {
    __shared__ float sfg[256];
    int row = blockIdx.x;
    int l = row & (L_ - 1);
    int t = threadIdx.x;
    int v = tok[row];
    if (t < DS_) {
        float m = tok_mu[(size_t)v * DS_ + t] + pos_mu[l * DS_ + t];
        mu[(size_t)row * DS_ + t] = m;
        mub16[(size_t)row * DS_ + t] = f2bf(m);
        float ivv = __expf(-tok_lv[(size_t)v * DS_ + t]);
        muivP[(size_t)t * BL_ + row] = packbf(m, ivv);
    }
    float fv = tok_f[(size_t)v * DF_ + t];
    feat[(size_t)row * DF_ + t] = fv;
    featb16[(size_t)row * DF_ + t] = f2bf(fv);
    sfg[t] = fv;
    if (t == 0) alpha[row] = sigmoidf_(tok_ra[v]);
    __syncthreads();
    if (t < 128) {
        int half = t >> 6, fl = t & 63;
        featP[(size_t)row * 128 + half * 64 + fl] =
            packbf(sfg[half * 128 + fl], sfg[half * 128 + fl + 64]);
    }
}

// query (mean of mu over L) + blob mixture with parallel product-scan. grid B_
__global__ __launch_bounds__(256) void k_queryblob(
    const float* __restrict__ mu, const float* __restrict__ blob_mu,
    const float* __restrict__ blob_lv, const float* __restrict__ blob_ra,
    const float* __restrict__ blob_f, float* __restrict__ blobm,
    float* __restrict__ tres) {
    __shared__ float red[256];
    __shared__ float sq[DS_];
    __shared__ float sa[NB_];
    __shared__ float sp[NB_];
    int b = blockIdx.x, t = threadIdx.x;
    int d = t & 63, c = t >> 6;
    float s = 0.f;
    for (int l = c; l < L_; l += 4) s += mu[((size_t)b * L_ + l) * DS_ + d];
    red[t] = s;
    __syncthreads();
    if (c == 0)
        sq[d] = (red[d] + red[64 + d] + red[128 + d] + red[192 + d]) * (1.f / L_);
    __syncthreads();
    for (int n = t; n < NB_; n += 256) {
        float d2 = 0.f;
        for (int dd = 0; dd < DS_; ++dd) {
            float diff = sq[dd] - blob_mu[n * DS_ + dd];
            d2 += __expf(-blob_lv[n * DS_ + dd]) * diff * diff;
        }
        float a = sigmoidf_(blob_ra[n]) * __expf(-0.5f * d2);
        sa[n] = a;
        sp[n] = 1.f - a;
    }
    __syncthreads();
    int n0 = t, n1 = t + 256;
    for (int s2 = 1; s2 < NB_; s2 <<= 1) {
        float t0 = (n0 >= s2) ? sp[n0 - s2] : 1.f;
        float t1 = (n1 >= s2) ? sp[n1 - s2] : 1.f;
        __syncthreads();
        sp[n0] *= t0;
        sp[n1] *= t1;
        __syncthreads();
    }
    float w0 = sa[n0] * (n0 ? sp[n0 - 1] : 1.f);
    float w1 = sa[n1] * sp[n1 - 1];
    __syncthreads();
    sa[n0] = w0;
    sa[n1] = w1;
    if (t == 0) tres[b] = sp[NB_ - 1];
    __syncthreads();
    float acc = 0.f;
    for (int n = 0; n < NB_; ++n) acc += sa[n] * blob_f[n * DF_ + t];
    blobm[b * DF_ + t] = acc;
}

// ---------------------------------------------------------------------------
// Attention v3: one 512-thread block per (b,i); wave w = head w.
// Per 64-j chunk: LDS-stage muivP (16KB) + featP (32KB) via global_load_lds,
// per-wave d2 + cumprod scan, PV from LDS, block-level early exit.
__global__ __launch_bounds__(512) void k_attn3(
    const float* __restrict__ q, const uint_t* __restrict__ muivP,
    const float* __restrict__ alpha, const uint_t* __restrict__ featP,
    ushort_t* __restrict__ mcatb) {
    __shared__ uint_t smiu[64 * 64];     // [d][jl]
    __shared__ uint_t sfp[64 * 128];     // [jl][c]
    __shared__ float sq[H_][64];
    __shared__ float swt[H_][64];
    __shared__ float sT[H_];
    int tid = threadIdx.x;
    int w = tid >> 6, lane = tid & 63;
    int bid = blockIdx.x;
    int b = bid >> 10, i = bid & (L_ - 1);
    int row = b * L_ + i;

    sq[w][lane] = q[(size_t)row * 512 + tid];
    float T = 1.f;
    float a0 = 0.f, a1 = 0.f, a2 = 0.f, a3 = 0.f;

    for (int j0 = 0; j0 <= i; j0 += 64) {
        __syncthreads();   // protects prev-chunk LDS reads; publishes sq/sT
        if (j0 > 0) {
            bool alive = false;
            #pragma unroll
            for (int h = 0; h < H_; ++h) alive |= (sT[h] >= 1e-12f);
            if (!alive) break;
        }
        // stage muiv chunk: wave w covers d = w*8 .. w*8+7 (2 width-16 issues)
        {
            const uint_t* src = muivP + b * L_ + j0;
            #pragma unroll
            for (int r = 0; r < 2; ++r) {
                int d = w * 8 + r * 4 + (lane >> 4);
                const uint_t* gp = src + (size_t)d * BL_ + (lane & 15) * 4;
                __builtin_amdgcn_global_load_lds((const AS1 uint_t*)gp,
                    (AS3 uint_t*)&smiu[(w * 8 + r * 4) * 64], 16, 0, 0);
            }
            const uint_t* fsrc = featP + (size_t)(b * L_ + j0) * 128 + w * 1024;
            #pragma unroll
            for (int it = 0; it < 4; ++it) {
                __builtin_amdgcn_global_load_lds((const AS1 uint_t*)(fsrc + it * 256 + lane * 4),
                    (AS3 uint_t*)&sfp[w * 1024 + it * 256], 16, 0, 0);
            }
        }
        __syncthreads();   // stage landed (barrier drains vmcnt)

        // phase A: d2 for this head's 64 j's
        int jj = j0 + lane;
        float d2 = 0.f;
        #pragma unroll 8
        for (int d = 0; d < 64; ++d) {
            uint_t v = smiu[d * 64 + lane];
            float m = bflo(v), iv = bfhi(v);
            float diff = sq[w][d] - m;
            d2 = fmaf(iv * diff, diff, d2);
        }
        float a = (jj <= i) ? alpha[b * L_ + jj] * __expf(-0.5f * d2) : 0.f;

        // phase B: wave product-scan of (1-a)
        float p = 1.f - a;
        #pragma unroll
        for (int s = 1; s < 64; s <<= 1) {
            float tt = __shfl_up(p, s, 64);
            if (lane >= s) p *= tt;
        }
        float Tex = __shfl_up(p, 1, 64);
        if (lane == 0) Tex = 1.f;
        swt[w][lane] = a * T * Tex;
        float Tch = __shfl(p, 63, 64);
        unsigned long long dead = __ballot(p < 1e-12f);
        int jn = i - j0 + 1;
        if (jn > 64) jn = 64;
        if (dead) {
            int cut = __builtin_ctzll(dead) + 1;
            if (cut < jn) jn = cut;
        }
        T *= Tch;
        if (lane == 0) sT[w] = T;

        // phase C: PV accumulate from LDS (packed quadrant pairs)
        for (int j = 0; j < jn; ++j) {
            float wj = swt[w][j];
            uint_t v0 = sfp[j * 128 + lane];
            uint_t v1 = sfp[j * 128 + 64 + lane];
            a0 = fmaf(wj, bflo(v0), a0);
            a1 = fmaf(wj, bfhi(v0), a1);
            a2 = fmaf(wj, bflo(v1), a2);
            a3 = fmaf(wj, bfhi(v1), a3);
        }
    }
    ushort_t* o = mcatb + (size_t)row * 2048 + w * 256 + lane;
    o[0] = f2bf(a0); o[64] = f2bf(a1); o[128] = f2bf(a2); o[192] = f2bf(a3);
}

// ---------------------------------------------------------------------------
// bf16 MFMA GEMM: C(M,N) = A(M,K)bf16 @ W(N,K)^T + bias.
// Optional two-segment A (segment boundary K1, both with row stride strideA);
// optional bf16 mirror output Cb. 2-phase double-buffered global_load_lds
// staging; chunk-major LDS; LDS-transposed coalesced epilogue.
template <int BM, int BN, int BK, int WGM, int WGN, bool NTS, bool WB16>
__global__ __launch_bounds__(256) void gemm_mfma2(
    const ushort_t* __restrict__ A, const ushort_t* __restrict__ A2, int K1,
    int strideA, const ushort_t* __restrict__ W, const float* __restrict__ bias,
    float* __restrict__ C, ushort_t* __restrict__ Cb, int M, int N, int K) {
    constexpr int WMF = BM / WGM / 16;
    constexpr int WNF = BN / WGN / 16;
    constexpr int KK  = BK / 32;
    constexpr int AHALF = BM * BK;
    constexpr int BHALF = BN * BK;
    constexpr int STAGE_B = 2 * (AHALF + BHALF) * 2;
    constexpr int EPI_B = BM * BN * 4;
    constexpr int SMEM_B = STAGE_B > EPI_B ? STAGE_B : EPI_B;
    __shared__ __align__(16) char smem[SMEM_B];
    ushort_t* As = (ushort_t*)smem;
    ushort_t* Bs = (ushort_t*)(smem + 2 * AHALF * 2);

    const int tid = threadIdx.x;
    const int wave = tid >> 6, lane = tid & 63;
    const int m0 = blockIdx.x * BM, n0 = blockIdx.y * BN;
    const int wr = wave / WGN, wc = wave % WGN;
    const int lr = lane & 15;
    const int q4 = lane >> 4;

    f32x4 acc[WMF][WNF] = {};

    auto stage = [&](int buf, int t) {
        const int k0g = t * BK;
        const ushort_t* Abase = (A2 != nullptr && k0g >= K1) ? A2 : A;
        const int kof = (A2 != nullptr && k0g >= K1) ? k0g - K1 : k0g;
        ushort_t* Ad = As + buf * AHALF;
        #pragma unroll
        for (int it = 0; it < (BM * BK / 8) / 256; ++it) {
            int cbase = it * 256 + wave * 64;
            int c = cbase + lane;
            int r = c & (BM - 1), c8 = c / BM;
            const ushort_t* gp = Abase + (size_t)(m0 + r) * strideA + kof + c8 * 8;
            __builtin_amdgcn_global_load_lds((const AS1 uint_t*)gp,
                                             (AS3 uint_t*)(Ad + cbase * 8), 16, 0, 0);
        }
        ushort_t* Bd = Bs + buf * BHALF;
        #pragma unroll
        for (int it = 0; it < (BN * BK / 8) / 256; ++it) {
            int cbase = it * 256 + wave * 64;
            int c = cbase + lane;
            int r = c & (BN - 1), c8 = c / BN;
            const ushort_t* gp = W + (size_t)(n0 + r) * K + k0g + c8 * 8;
            __builtin_amdgcn_global_load_lds((const AS1 uint_t*)gp,
                                             (AS3 uint_t*)(Bd + cbase * 8), 16, 0, 0);
        }
    };

    const int nsteps = K / BK;
    stage(0, 0);
    __syncthreads();
    for (int t = 0; t < nsteps; ++t) {
        const int cur = t & 1;
        if (t + 1 < nsteps) stage(cur ^ 1, t + 1);
        const ushort_t* Ab = As + cur * AHALF;
        const ushort_t* Bb = Bs + cur * BHALF;
        bf16x8 af[WMF][KK], bfr[WNF][KK];
        #pragma unroll
        for (int mi = 0; mi < WMF; ++mi)
            #pragma unroll
            for (int kk = 0; kk < KK; ++kk)
                af[mi][kk] = *reinterpret_cast<const bf16x8*>(
                    &Ab[((kk * 4 + q4) * BM + wr * (BM / WGM) + mi * 16 + lr) * 8]);
        #pragma unroll
        for (int ni = 0; ni < WNF; ++ni)
            #pragma unroll
            for (int kk = 0; kk < KK; ++kk)
                bfr[ni][kk] = *reinterpret_cast<const bf16x8*>(
                    &Bb[((kk * 4 + q4) * BN + wc * (BN / WGN) + ni * 16 + lr) * 8]);
        #pragma unroll
        for (int kk = 0; kk < KK; ++kk)
            #pragma unroll
            for (int mi = 0; mi < WMF; ++mi)
                #pragma unroll
                for (int ni = 0; ni < WNF; ++ni)
                    acc[mi][ni] = __builtin_amdgcn_mfma_f32_16x16x32_bf16(
                        af[mi][kk], bfr[ni][kk], acc[mi][ni], 0, 0, 0);
        __syncthreads();
    }

    float* tile = (float*)smem;
    #pragma unroll
    for (int mi = 0; mi < WMF; ++mi)
        #pragma unroll
        for (int ni = 0; ni < WNF; ++ni) {
            int col = wc * (BN / WGN) + ni * 16 + lr;
            float bv = bias[n0 + col];
            #pragma unroll
            for (int j = 0; j < 4; ++j) {
                int r2 = wr * (BM / WGM) + mi * 16 + q4 * 4 + j;
                tile[r2 * BN + col] = acc[mi][ni][j] + bv;
            }
        }
    __syncthreads();
    constexpr int EV = (BM * BN / 4) / 256;
    #pragma unroll
    for (int e = 0; e < EV; ++e) {
        int idx = e * 256 + tid;
        int r = idx / (BN / 4), c4 = idx % (BN / 4);
        f32x4 v = reinterpret_cast<const f32x4*>(tile)[idx];
        f32x4* dst = reinterpret_cast<f32x4*>(&C[(size_t)(m0 + r) * N + n0 + c4 * 4]);
        if (NTS) __builtin_nontemporal_store(v, dst);
        else *dst = v;
        if (WB16) {
            ushort4 ob = {f2bf(v[0]), f2bf(v[1]), f2bf(v[2]), f2bf(v[3])};
            *reinterpret_cast<ushort4*>(&Cb[(size_t)(m0 + r) * N + n0 + c4 * 4]) = ob;
        }
    }
}

// ---------------------------------------------------------------------------
// apply pass-0 update; maintains mu, mub16, muivP, alpha, feat, featb16, featP.
__global__ __launch_bounds__(256) void k_apply(
    const float* __restrict__ meaning, const float* __restrict__ agw,
    const float* __restrict__ agb, const float* __restrict__ dmu,
    const float* __restrict__ dffn, float* __restrict__ mu,
    ushort_t* __restrict__ mub16, uint_t* __restrict__ muivP,
    float* __restrict__ alpha, float* __restrict__ feat,
    ushort_t* __restrict__ featb16, uint_t* __restrict__ featP) {
    __shared__ float red[256];
    int row = blockIdx.x, t = threadIdx.x;
    float c0 = feat[(size_t)row * DF_ + t];
    float c1 = meaning[(size_t)row * DF_ + t];
    float s = block_reduce_sum(c0 * agw[t] + c1 * agw[256 + t], red);
    if (t == 0) alpha[row] *= sigmoidf_(s + agb[0]);
    if (t < DS_) {
        float m = mu[(size_t)row * DS_ + t] + dmu[(size_t)row * DS_ + t];
        mu[(size_t)row * DS_ + t] = m;
        mub16[(size_t)row * DS_ + t] = f2bf(m);
        uint_t v = muivP[(size_t)t * BL_ + row];
        muivP[(size_t)t * BL_ + row] = (v & 0xFFFF0000u) | (uint_t)f2bf(m);
    }
    float fn = c0 + dffn[(size_t)row * DF_ + t];
    feat[(size_t)row * DF_ + t] = fn;
    featb16[(size_t)row * DF_ + t] = f2bf(fn);
    red[t] = fn;
    __syncthreads();
    if (t < 128) {
        int half = t >> 6, fl = t & 63;
        featP[(size_t)row * 128 + half * 64 + fl] =
            packbf(red[half * 128 + fl], red[half * 128 + fl + 64]);
    }
}

// gate + fuse + layernorm -> bf16 h.  grid BL_
__global__ __launch_bounds__(256) void k_fused_ln(
    const float* __restrict__ meaning, const float* __restrict__ blobm,
    const float* __restrict__ tres, const float* __restrict__ bgw,
    const float* __restrict__ bgb, const float* __restrict__ ln_g,
    const float* __restrict__ ln_b, ushort_t* __restrict__ houtb) {
    __shared__ float red[256];
    int row = blockIdx.x, t = threadIdx.x;
    int b = row >> 10;
    float m = meaning[(size_t)row * DF_ + t];
    float be = blobm[b * DF_ + t];
    float tr = tres[b];
    float gsum = block_reduce_sum(be * bgw[t] + m * bgw[256 + t], red);
    float gate = sigmoidf_(gsum + bgb[0]);
    float f = (1.f - tr) * gate * be + tr * m;
    float mean = block_reduce_sum(f, red) * (1.f / DF_);
    float d = f - mean;
    float var = block_reduce_sum(d * d, red) * (1.f / DF_);
    houtb[(size_t)row * DF_ + t] = f2bf(d * rsqrtf(var + EPS_) * ln_g[t] + ln_b[t]);
}

extern "C" void kernel_launch(void* const* d_in, const int* in_sizes, int n_in,
                              void* d_out, int out_size, void* d_ws, size_t ws_size,
                              hipStream_t stream) {
    const int*   tok      = (const int*)d_in[0];
    const float* tok_mu   = (const float*)d_in[1];
    const float* tok_lv   = (const float*)d_in[2];
    const float* tok_ra   = (const float*)d_in[3];
    const float* tok_f    = (const float*)d_in[4];
    const float* pos_mu   = (const float*)d_in[5];
    const float* qproj_w  = (const float*)d_in[6];
    const float* qproj_b  = (const float*)d_in[7];
    const float* hproj_w  = (const float*)d_in[8];
    const float* hproj_b  = (const float*)d_in[9];
    const float* mu_up_w  = (const float*)d_in[10];
    const float* mu_up_b  = (const float*)d_in[11];
    const float* agate_w  = (const float*)d_in[12];
    const float* agate_b  = (const float*)d_in[13];
    const float* ffn_w    = (const float*)d_in[14];
    const float* ffn_b    = (const float*)d_in[15];
    const float* ln_g     = (const float*)d_in[16];
    const float* ln_b     = (const float*)d_in[17];
    const float* lm_w     = (const float*)d_in[18];
    const float* lm_b     = (const float*)d_in[19];
    const float* blob_mu  = (const float*)d_in[20];
    const float* blob_lv  = (const float*)d_in[21];
    const float* blob_ra  = (const float*)d_in[22];
    const float* blob_f   = (const float*)d_in[23];
    const float* bgate_w  = (const float*)d_in[24];
    const float* bgate_b  = (const float*)d_in[25];
    float* out = (float*)d_out;

    float* ws = (float*)d_ws;
    float* mu      = ws;                        // BL*64
    float* alpha   = mu + BL_ * DS_;            // BL
    float* feat    = alpha + BL_;               // BL*256
    float* blobm   = feat + BL_ * DF_;          // B*256
    float* tres    = blobm + B_ * DF_;          // pad 64
    float* q       = tres + 64;                 // BL*512
    float* meaning = q + BL_ * 512;             // BL*256
    float* dmu     = meaning + BL_ * DF_;       // BL*64
    float* dffn    = dmu + BL_ * DS_;           // BL*256
    uint_t* muivP  = (uint_t*)(dffn + BL_ * DF_);         // 64*BL
    uint_t* featP  = muivP + (size_t)DS_ * BL_;           // BL*128
    ushort_t* mub16 = (ushort_t*)(featP + (size_t)BL_ * 128); // BL*64
    ushort_t* featb16 = mub16 + (size_t)BL_ * DS_;        // BL*256
    ushort_t* meanb16 = featb16 + (size_t)BL_ * DF_;      // BL*256
    ushort_t* mcatb = meanb16 + (size_t)BL_ * DF_;        // BL*2048
    ushort_t* hbufb = mcatb + (size_t)BL_ * 2048;         // BL*256
    ushort_t* wbf   = hbufb + (size_t)BL_ * DF_;          // V*256
    ushort_t* hpwbf = wbf + (size_t)V_ * DF_;             // 256*2048
    ushort_t* qpwbf = hpwbf + (size_t)DF_ * 2048;         // 512*64
    ushort_t* muwbf = qpwbf + (size_t)512 * 64;           // 64*512
    ushort_t* ffnwbf = muwbf + (size_t)64 * 512;          // 256*512

    k_cvt5<<<8704, 256, 0, stream>>>(qproj_w, qpwbf, mu_up_w, muwbf,
                                     ffn_w, ffnwbf, hproj_w, hpwbf, lm_w, wbf);

    k_gather<<<BL_, 256, 0, stream>>>(tok, tok_mu, tok_lv, tok_ra, tok_f, pos_mu,
                                      mu, mub16, muivP, alpha, feat, featb16, featP);
    k_queryblob<<<B_, 256, 0, stream>>>(mu, blob_mu, blob_lv, blob_ra, blob_f,
                                        blobm, tres);

    for (int p = 0; p < 2; ++p) {
        gemm_mfma2<32, 32, 64, 2, 2, false, false>
            <<<dim3(BL_ / 32, 512 / 32), 256, 0, stream>>>(
            mub16, nullptr, 0, DS_, qpwbf, qproj_b, q, nullptr, BL_, 512, DS_);
        k_attn3<<<BL_, 512, 0, stream>>>(q, muivP, alpha, featP, mcatb);
        if (p == 0) {
            gemm_mfma2<32, 32, 64, 2, 2, false, true>
                <<<dim3(BL_ / 32, DF_ / 32), 256, 0, stream>>>(
                mcatb, nullptr, 0, H_ * DF_, hpwbf, hproj_b, meaning, meanb16,
                BL_, DF_, H_ * DF_);
            gemm_mfma2<32, 32, 64, 2, 2, false, false>
                <<<dim3(BL_ / 32, DS_ / 32), 256, 0, stream>>>(
                featb16, meanb16, DF_, DF_, muwbf, mu_up_b, dmu, nullptr,
                BL_, DS_, 512);
            gemm_mfma2<32, 32, 64, 2, 2, false, false>
                <<<dim3(BL_ / 32, DF_ / 32), 256, 0, stream>>>(
                featb16, meanb16, DF_, DF_, ffnwbf, ffn_b, dffn, nullptr,
                BL_, DF_, 512);
            k_apply<<<BL_, 256, 0, stream>>>(meaning, agate_w, agate_b, dmu, dffn,
                                             mu, mub16, muivP, alpha, feat,
                                             featb16, featP);
        } else {
            gemm_mfma2<32, 32, 64, 2, 2, false, false>
                <<<dim3(BL_ / 32, DF_ / 32), 256, 0, stream>>>(
                mcatb, nullptr, 0, H_ * DF_, hpwbf, hproj_b, meaning, nullptr,
                BL_, DF_, H_ * DF_);
        }
    }

    k_fused_ln<<<BL_, 256, 0, stream>>>(meaning, blobm, tres, bgate_w, bgate_b,
                                        ln_g, ln_b, hbufb);
    gemm_mfma2<128, 128, 64, 2, 2, true, false>
        <<<dim3(BL_ / 128, V_ / 128), 256, 0, stream>>>(
        hbufb, nullptr, 0, DF_, wbf, lm_b, out, nullptr, BL_, V_, DF_);
}